// Round 2
// baseline (412.516 us; speedup 1.0000x reference)
//
#include <hip/hip_runtime.h>
#include <cstdint>

#define DEVFN static __device__ __forceinline__

typedef __bf16 bf16x8 __attribute__((ext_vector_type(8)));
typedef float f32x4 __attribute__((ext_vector_type(4)));

DEVFN unsigned short f2bf(float f) {
  unsigned u = __float_as_uint(f);
  u += 0x7fffu + ((u >> 16) & 1u);           // round-to-nearest-even
  return (unsigned short)(u >> 16);
}
DEVFN float bf2f(unsigned short h) { return __uint_as_float(((unsigned)h) << 16); }
DEVFN void async16(const void* g, void* l) {
  __builtin_amdgcn_global_load_lds((__attribute__((address_space(1))) const void*)g,
                                   (__attribute__((address_space(3))) void*)l, 16, 0, 0);
}

// ---------------- rope table ------------------------------------------------
// rope[t*64+d]: d<32 -> cos(t*f_d), else sin(t*f_{d-32}); f_i = exp(-i*ln(1e4)/32)
__global__ __launch_bounds__(256) void k_rope(float* __restrict__ rope) {
  int g = blockIdx.x * 256 + threadIdx.x;
  int t = g >> 6, dd = g & 63, i = dd & 31;
  float fr = __expf(-0.2878231366242558f * (float)i);
  float ang = (float)t * fr;
  rope[g] = (dd < 32) ? cosf(ang) : sinf(ang);
}

// ---------------- weight transpose (K x N f32 -> N x K bf16) + col sq-norms -
__global__ __launch_bounds__(256) void k_transpose(const float* __restrict__ W,
    unsigned short* __restrict__ Wt, float* __restrict__ cn, int N, int K) {
  __shared__ float tile[32][33];
  __shared__ float part[8][32];
  int tx = threadIdx.x & 31, ty = threadIdx.x >> 5;
  int tn = blockIdx.x, tk = blockIdx.y;
  float acc = 0.f;
  #pragma unroll
  for (int j = 0; j < 4; ++j) {
    int r = ty + j * 8;
    float v = W[(long)(tk * 32 + r) * N + tn * 32 + tx];
    tile[r][tx] = v;
    acc += v * v;
  }
  part[ty][tx] = acc;
  __syncthreads();
  #pragma unroll
  for (int j = 0; j < 4; ++j) {
    int rr = ty + j * 8;
    Wt[(long)(tn * 32 + rr) * K + tk * 32 + tx] = f2bf(tile[tx][rr]);
  }
  if (ty == 0) {
    float s = part[0][tx];
    #pragma unroll
    for (int jj = 1; jj < 8; ++jj) s += part[jj][tx];
    atomicAdd(&cn[tn * 32 + tx], s);
  }
}

// ---------------- layernorm (f32 in) -> bf16 h + row sum(h^2) ---------------
__global__ __launch_bounds__(256) void k_ln(const float* __restrict__ x,
    const float* __restrict__ g, unsigned short* __restrict__ h, float* __restrict__ row2) {
  int row = blockIdx.x, tid = threadIdx.x;
  const float* xr = x + (long)row * 768;
  float v0 = xr[tid], v1 = xr[tid + 256], v2 = xr[tid + 512];
  float s = v0 + v1 + v2;
  float ss = v0 * v0 + v1 * v1 + v2 * v2;
  #pragma unroll
  for (int o = 32; o; o >>= 1) { s += __shfl_xor(s, o); ss += __shfl_xor(ss, o); }
  __shared__ float red[12];
  int wv = tid >> 6;
  if ((tid & 63) == 0) { red[wv] = s; red[wv + 4] = ss; }
  __syncthreads();
  s = red[0] + red[1] + red[2] + red[3];
  ss = red[4] + red[5] + red[6] + red[7];
  float mu = s * (1.f / 768.f);
  float var = ss * (1.f / 768.f) - mu * mu;
  float rs = rsqrtf(var + 1e-6f);
  float h0 = (v0 - mu) * rs * g[tid];
  float h1 = (v1 - mu) * rs * g[tid + 256];
  float h2 = (v2 - mu) * rs * g[tid + 512];
  unsigned short* hr = h + (long)row * 768;
  hr[tid] = f2bf(h0); hr[tid + 256] = f2bf(h1); hr[tid + 512] = f2bf(h2);
  float p = h0 * h0 + h1 * h1 + h2 * h2;
  #pragma unroll
  for (int o = 32; o; o >>= 1) p += __shfl_xor(p, o);
  if ((tid & 63) == 0) red[8 + wv] = p;
  __syncthreads();
  if (tid == 0) row2[row] = red[8] + red[9] + red[10] + red[11];
}

// ---------------- row sum of squares of a bf16 matrix -----------------------
__global__ __launch_bounds__(256) void k_row2(const unsigned short* __restrict__ m,
                                              float* __restrict__ row2, int C) {
  int row = blockIdx.x, tid = threadIdx.x;
  const unsigned short* r = m + (long)row * C;
  float s = 0.f;
  for (int c = tid; c < C; c += 256) { float v = bf2f(r[c]); s += v * v; }
  #pragma unroll
  for (int o = 32; o; o >>= 1) s += __shfl_xor(s, o);
  __shared__ float red[4];
  if ((tid & 63) == 0) red[tid >> 6] = s;
  __syncthreads();
  if (tid == 0) row2[row] = red[0] + red[1] + red[2] + red[3];
}

// ---------------- yat GEMM: C = epilogue(A[MxK] @ Bt[NxK]^T) ----------------
constexpr int M_QKV = 0, M_AO = 1, M_FC = 2, M_GATE = 3, M_PROJ = 4;

struct GemmArgs {
  const unsigned short* A; const unsigned short* Bt;
  const float* arow2; const float* wcol2; const float* bias; const float* alpha;
  int K, N;
  const float* rope;                                    // QKV
  unsigned short* qo; unsigned short* ko; unsigned short* vo;  // QKV
  const float* xf; float* xo;                           // AO: residual in/out (f32)
  unsigned short* ob;                                   // FC: g1 out; GATE: mlp out
  const unsigned short* g1;                             // GATE in
  const float* xo_in; float* outf;                      // PROJ: residual in, f32 out
};

template <int MODE>
__global__ __launch_bounds__(256) void k_gemm(GemmArgs p) {
  __shared__ __align__(16) unsigned short As[128 * 32];
  __shared__ __align__(16) unsigned short Bs[128 * 32];
  const int tid = threadIdx.x, wave = tid >> 6, lane = tid & 63;
  const int quad = lane >> 4, l = lane & 15;
  const int bm = blockIdx.x * 128, bn = blockIdx.y * 128;
  const int wm = (wave & 1) * 64, wn = (wave >> 1) * 64;
  const int K = p.K;
  const f32x4 fzero = {0.f, 0.f, 0.f, 0.f};
  f32x4 acc[4][4];
  #pragma unroll
  for (int i = 0; i < 4; ++i) {
    #pragma unroll
    for (int j = 0; j < 4; ++j) acc[i][j] = fzero;
  }
  const int sw = (l >> 1) & 3;   // LDS chunk xor-swizzle
  for (int k0 = 0; k0 < K; k0 += 32) {
    __syncthreads();
    #pragma unroll
    for (int it = 0; it < 2; ++it) {
      int ci = tid + it * 256;
      int r = ci >> 2;
      int c = (ci & 3) ^ ((r >> 1) & 3);
      async16(p.A + (long)(bm + r) * K + k0 + c * 8, &As[ci * 8]);
      async16(p.Bt + (long)(bn + r) * K + k0 + c * 8, &Bs[ci * 8]);
    }
    __builtin_amdgcn_s_waitcnt(0);
    __syncthreads();
    bf16x8 af[4], bfv[4];
    #pragma unroll
    for (int mi = 0; mi < 4; ++mi)
      af[mi] = *(const bf16x8*)&As[(wm + mi * 16 + l) * 32 + ((quad ^ sw) * 8)];
    #pragma unroll
    for (int ni = 0; ni < 4; ++ni)
      bfv[ni] = *(const bf16x8*)&Bs[(wn + ni * 16 + l) * 32 + ((quad ^ sw) * 8)];
    #pragma unroll
    for (int mi = 0; mi < 4; ++mi) {
      #pragma unroll
      for (int ni = 0; ni < 4; ++ni)
        acc[mi][ni] = __builtin_amdgcn_mfma_f32_16x16x32_bf16(af[mi], bfv[ni], acc[mi][ni], 0, 0, 0);
    }
  }
  // epilogue:  v = ((y^2)/(||a||^2+||w||^2-2y+eps) + bias) * (sqrt(N)/log1p(N))^alpha
  const float al = p.alpha[0];
  const float nn = (float)p.N;
  const float ys = powf(sqrtf(nn) / log1pf(nn), al);
  #pragma unroll
  for (int ni = 0; ni < 4; ++ni) {
    const int j = bn + wn + ni * 16 + l;
    const float w2 = p.wcol2[j];
    const float bj = p.bias[j];
    int s3 = 0, hh = 0, dd = 0;
    if constexpr (MODE == M_QKV) { s3 = j / 768; int rem = j - s3 * 768; hh = rem >> 6; dd = rem & 63; }
    #pragma unroll
    for (int mi = 0; mi < 4; ++mi) {
      #pragma unroll
      for (int rg = 0; rg < 4; ++rg) {
        const int i = bm + wm + mi * 16 + quad * 4 + rg;   // C-layout: row = quad*4+reg
        const float y = acc[mi][ni][rg];
        const float dist = p.arow2[i] + w2 - 2.f * y + 1e-6f;
        float v = (y * y / dist + bj) * ys;
        if constexpr (MODE == M_QKV) {
          int b = i >> 10, t = i & 1023;
          if (s3 == 2) {
            p.vo[((long)(b * 12 + hh) * 64 + dd) * 1024 + t] = f2bf(v);      // V^T (B,H,D,T)
          } else {
            float ro = p.rope[t * 64 + dd];
            unsigned short* dst = (s3 == 0) ? p.qo : p.ko;                   // (B,H,T,D)
            dst[((long)(b * 12 + hh) * 1024 + t) * 64 + dd] = f2bf(v * ro);
          }
        } else if constexpr (MODE == M_AO) {
          long idx = (long)i * 768 + j;
          p.xo[idx] = p.xf[idx] + v;
        } else if constexpr (MODE == M_FC) {
          p.ob[(long)i * 3072 + j] = f2bf(v);
        } else if constexpr (MODE == M_GATE) {
          float u = v;
          float ge = 0.5f * u * (1.f + tanhf(0.7978845608028654f * (u + 0.044715f * u * u * u)));
          long idx = (long)i * 3072 + j;
          p.ob[idx] = f2bf(ge * bf2f(p.g1[idx]));
        } else {  // M_PROJ -> f32 output
          long idx = (long)i * 768 + j;
          p.outf[idx] = p.xo_in[idx] + v;
        }
      }
    }
  }
}

// ---------------- flash attention: 64-row Q tiles, causal -------------------
__global__ __launch_bounds__(256) void k_attn(const unsigned short* __restrict__ qb,
    const unsigned short* __restrict__ kb, const unsigned short* __restrict__ vb,
    unsigned short* __restrict__ ob) {
  __shared__ __align__(16) unsigned short Qs[64 * 64];
  __shared__ __align__(16) unsigned short Ks[64 * 64];
  __shared__ __align__(16) unsigned short Vs[64 * 64];
  __shared__ __align__(16) unsigned short Ps[4 * 16 * 64];
  const int tid = threadIdx.x, wave = tid >> 6, lane = tid & 63;
  const int quad = lane >> 4, l = lane & 15;
  const int qt = blockIdx.x, bh = blockIdx.y;
  const int b = bh / 12, hh = bh % 12;
  const int q0 = qt * 64;
  const f32x4 fzero = {0.f, 0.f, 0.f, 0.f};

  const unsigned short* qg = qb + ((long)bh * 1024 + q0) * 64;
  #pragma unroll
  for (int it = 0; it < 2; ++it) {
    int ci = tid + it * 256;
    int r = ci >> 3;
    int c = (ci & 7) ^ (r & 7);
    async16(qg + (long)r * 64 + c * 8, &Qs[ci * 8]);
  }
  __builtin_amdgcn_s_waitcnt(0);
  __syncthreads();
  bf16x8 aq[2];
  #pragma unroll
  for (int ks = 0; ks < 2; ++ks)
    aq[ks] = *(const bf16x8*)&Qs[(wave * 16 + l) * 64 + (((ks * 4 + quad) ^ (l & 7)) * 8)];

  f32x4 O[4];
  float mi_[4], li[4];
  #pragma unroll
  for (int f = 0; f < 4; ++f) O[f] = fzero;
  #pragma unroll
  for (int r = 0; r < 4; ++r) { mi_[r] = -1e30f; li[r] = 0.f; }

  for (int jt = 0; jt <= qt; ++jt) {
    __syncthreads();
    const unsigned short* kg = kb + ((long)bh * 1024 + jt * 64) * 64;
    const unsigned short* vg = vb + (long)bh * 64 * 1024 + jt * 64;
    #pragma unroll
    for (int it = 0; it < 2; ++it) {
      int ci = tid + it * 256;
      int r = ci >> 3;
      int c = (ci & 7) ^ (r & 7);
      async16(kg + (long)r * 64 + c * 8, &Ks[ci * 8]);
      async16(vg + (long)r * 1024 + c * 8, &Vs[ci * 8]);
    }
    __builtin_amdgcn_s_waitcnt(0);
    __syncthreads();

    f32x4 S[4];
    #pragma unroll
    for (int f = 0; f < 4; ++f) S[f] = fzero;
    #pragma unroll
    for (int ks = 0; ks < 2; ++ks) {
      #pragma unroll
      for (int f = 0; f < 4; ++f) {
        bf16x8 bk = *(const bf16x8*)&Ks[(f * 16 + l) * 64 + (((ks * 4 + quad) ^ (l & 7)) * 8)];
        S[f] = __builtin_amdgcn_mfma_f32_16x16x32_bf16(aq[ks], bk, S[f], 0, 0, 0);
      }
    }
    const bool diag = (jt == qt);
    #pragma unroll
    for (int f = 0; f < 4; ++f) {
      #pragma unroll
      for (int r = 0; r < 4; ++r) {
        float v = S[f][r] * 0.125f;
        if (diag && (f * 16 + l > wave * 16 + quad * 4 + r)) v = -1e30f;
        S[f][r] = v;
      }
    }
    #pragma unroll
    for (int r = 0; r < 4; ++r) {
      float mx = fmaxf(fmaxf(S[0][r], S[1][r]), fmaxf(S[2][r], S[3][r]));
      #pragma unroll
      for (int o = 8; o; o >>= 1) mx = fmaxf(mx, __shfl_xor(mx, o));
      float mnew = fmaxf(mi_[r], mx);
      float alr = __expf(mi_[r] - mnew);
      float sum = 0.f;
      #pragma unroll
      for (int f = 0; f < 4; ++f) {
        float e = __expf(S[f][r] - mnew);
        S[f][r] = e;
        sum += e;
      }
      #pragma unroll
      for (int o = 8; o; o >>= 1) sum += __shfl_xor(sum, o);
      li[r] = li[r] * alr + sum;
      #pragma unroll
      for (int f = 0; f < 4; ++f) O[f][r] *= alr;
      mi_[r] = mnew;
    }
    // P: C-layout -> LDS strip (swizzled) -> A-layout
    #pragma unroll
    for (int f = 0; f < 4; ++f) {
      #pragma unroll
      for (int r = 0; r < 4; ++r) {
        int i = quad * 4 + r;
        int j = f * 16 + l;
        int pch = (j >> 3) ^ (i & 7);
        Ps[wave * 1024 + i * 64 + pch * 8 + (j & 7)] = f2bf(S[f][r]);
      }
    }
    #pragma unroll
    for (int ks = 0; ks < 2; ++ks) {
      bf16x8 ap = *(const bf16x8*)&Ps[wave * 1024 + l * 64 + (((ks * 4 + quad) ^ (l & 7)) * 8)];
      #pragma unroll
      for (int f = 0; f < 4; ++f) {
        bf16x8 bv = *(const bf16x8*)&Vs[(f * 16 + l) * 64 + (((ks * 4 + quad) ^ (l & 7)) * 8)];
        O[f] = __builtin_amdgcn_mfma_f32_16x16x32_bf16(ap, bv, O[f], 0, 0, 0);
      }
    }
  }
  #pragma unroll
  for (int f = 0; f < 4; ++f) {
    #pragma unroll
    for (int r = 0; r < 4; ++r) {
      int t = q0 + wave * 16 + quad * 4 + r;
      int dd = f * 16 + l;
      float v = O[f][r] / li[r];
      ob[((long)(b * 1024 + t) * 12 + hh) * 64 + dd] = f2bf(v);  // (B,T,H,D) == (B,T,C)
    }
  }
}

// ---------------- host ------------------------------------------------------
extern "C" void kernel_launch(void* const* d_in, const int* in_sizes, int n_in,
                              void* d_out, int out_size, void* d_ws, size_t ws_size,
                              hipStream_t stream) {
  (void)in_sizes; (void)n_in; (void)out_size;
  char* w = (char*)d_ws;
  size_t off = 0;
  auto alloc = [&](size_t bytes) -> void* {
    void* p = w + off;
    off = (off + bytes + 255) & ~(size_t)255;
    return p;
  };
  float* rope            = (float*)alloc(65536 * 4);
  unsigned short* wtqkv  = (unsigned short*)alloc((size_t)2304 * 768 * 2);
  unsigned short* wtao   = (unsigned short*)alloc((size_t)768 * 768 * 2);
  unsigned short* wtfc   = (unsigned short*)alloc((size_t)3072 * 768 * 2);
  unsigned short* wtgate = (unsigned short*)alloc((size_t)3072 * 768 * 2);
  unsigned short* wtproj = (unsigned short*)alloc((size_t)768 * 3072 * 2);
  float* wcol2           = (float*)alloc(9984 * 4);
  unsigned short* h1     = (unsigned short*)alloc((size_t)2048 * 768 * 2);
  float* hrow1           = (float*)alloc(2048 * 4);
  unsigned short* qbuf   = (unsigned short*)alloc((size_t)2048 * 768 * 2);
  unsigned short* kbuf   = (unsigned short*)alloc((size_t)2048 * 768 * 2);
  unsigned short* vbuf   = (unsigned short*)alloc((size_t)2048 * 768 * 2);
  unsigned short* obuf   = (unsigned short*)alloc((size_t)2048 * 768 * 2);
  float* orow2           = (float*)alloc(2048 * 4);
  float* xo              = (float*)alloc((size_t)2048 * 768 * 4);
  unsigned short* h2     = (unsigned short*)alloc((size_t)2048 * 768 * 2);
  float* hrow2           = (float*)alloc(2048 * 4);
  unsigned short* g1     = (unsigned short*)alloc((size_t)2048 * 3072 * 2);
  unsigned short* mlp    = (unsigned short*)alloc((size_t)2048 * 3072 * 2);
  float* mlprow2         = (float*)alloc(2048 * 4);
  if (off > ws_size) return;

  float* c_qkv  = wcol2 + 0;
  float* c_ao   = wcol2 + 2304;
  float* c_fc   = wcol2 + 3072;
  float* c_gate = wcol2 + 6144;
  float* c_proj = wcol2 + 9216;

  const float* xin = (const float*)d_in[0];

  // 1) rope table
  k_rope<<<256, 256, 0, stream>>>(rope);

  // 2) weight transpose + col norms (f32 weights -> bf16 B^T)
  hipMemsetAsync(wcol2, 0, 9984 * 4, stream);
  k_transpose<<<dim3(72, 24), 256, 0, stream>>>((const float*)d_in[3],  wtqkv,  c_qkv,  2304, 768);
  k_transpose<<<dim3(24, 24), 256, 0, stream>>>((const float*)d_in[6],  wtao,   c_ao,   768,  768);
  k_transpose<<<dim3(96, 24), 256, 0, stream>>>((const float*)d_in[10], wtfc,   c_fc,   3072, 768);
  k_transpose<<<dim3(96, 24), 256, 0, stream>>>((const float*)d_in[13], wtgate, c_gate, 3072, 768);
  k_transpose<<<dim3(24, 96), 256, 0, stream>>>((const float*)d_in[16], wtproj, c_proj, 768,  3072);

  // 3) LN1 (x f32 direct)
  k_ln<<<2048, 256, 0, stream>>>(xin, (const float*)d_in[2], h1, hrow1);

  // 4) QKV yat GEMM (+rope, scatter q/k/v)
  GemmArgs gq = {};
  gq.A = h1; gq.Bt = wtqkv; gq.arow2 = hrow1; gq.wcol2 = c_qkv;
  gq.bias = (const float*)d_in[4]; gq.alpha = (const float*)d_in[5];
  gq.K = 768; gq.N = 2304;
  gq.rope = rope; gq.qo = qbuf; gq.ko = kbuf; gq.vo = vbuf;
  k_gemm<M_QKV><<<dim3(16, 18), 256, 0, stream>>>(gq);

  // 5) attention
  k_attn<<<dim3(16, 24), 256, 0, stream>>>(qbuf, kbuf, vbuf, obuf);

  // 6) row norms of attention output
  k_row2<<<2048, 256, 0, stream>>>(obuf, orow2, 768);

  // 7) AO yat GEMM + residual -> xo (f32)
  GemmArgs ga = {};
  ga.A = obuf; ga.Bt = wtao; ga.arow2 = orow2; ga.wcol2 = c_ao;
  ga.bias = (const float*)d_in[7]; ga.alpha = (const float*)d_in[8];
  ga.K = 768; ga.N = 768;
  ga.xf = xin; ga.xo = xo;
  k_gemm<M_AO><<<dim3(16, 6), 256, 0, stream>>>(ga);

  // 8) LN2
  k_ln<<<2048, 256, 0, stream>>>(xo, (const float*)d_in[9], h2, hrow2);

  // 9) FC yat GEMM -> g1  (reference's "gate" = yat(h, w_fc))
  GemmArgs gf = {};
  gf.A = h2; gf.Bt = wtfc; gf.arow2 = hrow2; gf.wcol2 = c_fc;
  gf.bias = (const float*)d_in[11]; gf.alpha = (const float*)d_in[12];
  gf.K = 768; gf.N = 3072;
  gf.ob = g1;
  k_gemm<M_FC><<<dim3(16, 24), 256, 0, stream>>>(gf);

  // 10) GATE yat GEMM -> mlp = gelu(u) * g1
  GemmArgs gg = {};
  gg.A = h2; gg.Bt = wtgate; gg.arow2 = hrow2; gg.wcol2 = c_gate;
  gg.bias = (const float*)d_in[14]; gg.alpha = (const float*)d_in[15];
  gg.K = 768; gg.N = 3072;
  gg.ob = mlp; gg.g1 = g1;
  k_gemm<M_GATE><<<dim3(16, 24), 256, 0, stream>>>(gg);

  // 11) row norms of mlp
  k_row2<<<2048, 256, 0, stream>>>(mlp, mlprow2, 3072);

  // 12) PROJ yat GEMM + residual -> out (f32)
  GemmArgs gp = {};
  gp.A = mlp; gp.Bt = wtproj; gp.arow2 = mlprow2; gp.wcol2 = c_proj;
  gp.bias = (const float*)d_in[17]; gp.alpha = (const float*)d_in[18];
  gp.K = 3072; gp.N = 768;
  gp.xo_in = xo; gp.outf = (float*)d_out;
  k_gemm<M_PROJ><<<dim3(16, 6), 256, 0, stream>>>(gp);
}

// Round 3
// 358.186 us; speedup vs baseline: 1.1517x; 1.1517x over previous
//
#include <hip/hip_runtime.h>
#include <cstdint>

#define DEVFN static __device__ __forceinline__

typedef __bf16 bf16x8 __attribute__((ext_vector_type(8)));
typedef float f32x4 __attribute__((ext_vector_type(4)));
typedef unsigned short us4 __attribute__((ext_vector_type(4)));

DEVFN unsigned short f2bf(float f) {
  unsigned u = __float_as_uint(f);
  u += 0x7fffu + ((u >> 16) & 1u);           // round-to-nearest-even
  return (unsigned short)(u >> 16);
}
DEVFN float bf2f(unsigned short h) { return __uint_as_float(((unsigned)h) << 16); }
DEVFN void async16(const void* g, void* l) {
  __builtin_amdgcn_global_load_lds((__attribute__((address_space(1))) const void*)g,
                                   (__attribute__((address_space(3))) void*)l, 16, 0, 0);
}
DEVFN float gelu_t(float u) {
  return 0.5f * u * (1.f + tanhf(0.7978845608028654f * (u + 0.044715f * u * u * u)));
}

// ---------------- rope table ------------------------------------------------
__global__ __launch_bounds__(256) void k_rope(float* __restrict__ rope) {
  int g = blockIdx.x * 256 + threadIdx.x;
  int t = g >> 6, dd = g & 63, i = dd & 31;
  float fr = __expf(-0.2878231366242558f * (float)i);   // ln(1e4)/32
  float ang = (float)t * fr;
  rope[g] = (dd < 32) ? cosf(ang) : sinf(ang);
}

// ---------------- weight transpose (K x N f32 -> N x K bf16) + col sq-norms -
__global__ __launch_bounds__(256) void k_transpose(const float* __restrict__ W,
    unsigned short* __restrict__ Wt, float* __restrict__ cn, int N, int K) {
  __shared__ float tile[32][33];
  __shared__ float part[8][32];
  int tx = threadIdx.x & 31, ty = threadIdx.x >> 5;
  int tn = blockIdx.x, tk = blockIdx.y;
  float acc = 0.f;
  #pragma unroll
  for (int j = 0; j < 4; ++j) {
    int r = ty + j * 8;
    float v = W[(long)(tk * 32 + r) * N + tn * 32 + tx];
    tile[r][tx] = v;
    acc += v * v;
  }
  part[ty][tx] = acc;
  __syncthreads();
  #pragma unroll
  for (int j = 0; j < 4; ++j) {
    int rr = ty + j * 8;
    Wt[(long)(tn * 32 + rr) * K + tk * 32 + tx] = f2bf(tile[tx][rr]);
  }
  if (ty == 0) {
    float s = part[0][tx];
    #pragma unroll
    for (int jj = 1; jj < 8; ++jj) s += part[jj][tx];
    atomicAdd(&cn[tn * 32 + tx], s);
  }
}

// ---------------- layernorm (f32 in) -> bf16 h + row sum(h^2) ---------------
__global__ __launch_bounds__(256) void k_ln(const float* __restrict__ x,
    const float* __restrict__ g, unsigned short* __restrict__ h, float* __restrict__ row2) {
  int row = blockIdx.x, tid = threadIdx.x;
  const float* xr = x + (long)row * 768;
  float v0 = xr[tid], v1 = xr[tid + 256], v2 = xr[tid + 512];
  float s = v0 + v1 + v2;
  float ss = v0 * v0 + v1 * v1 + v2 * v2;
  #pragma unroll
  for (int o = 32; o; o >>= 1) { s += __shfl_xor(s, o); ss += __shfl_xor(ss, o); }
  __shared__ float red[12];
  int wv = tid >> 6;
  if ((tid & 63) == 0) { red[wv] = s; red[wv + 4] = ss; }
  __syncthreads();
  s = red[0] + red[1] + red[2] + red[3];
  ss = red[4] + red[5] + red[6] + red[7];
  float mu = s * (1.f / 768.f);
  float var = ss * (1.f / 768.f) - mu * mu;
  float rs = rsqrtf(var + 1e-6f);
  float h0 = (v0 - mu) * rs * g[tid];
  float h1 = (v1 - mu) * rs * g[tid + 256];
  float h2 = (v2 - mu) * rs * g[tid + 512];
  unsigned short* hr = h + (long)row * 768;
  hr[tid] = f2bf(h0); hr[tid + 256] = f2bf(h1); hr[tid + 512] = f2bf(h2);
  float p = h0 * h0 + h1 * h1 + h2 * h2;
  #pragma unroll
  for (int o = 32; o; o >>= 1) p += __shfl_xor(p, o);
  if ((tid & 63) == 0) red[8 + wv] = p;
  __syncthreads();
  if (tid == 0) row2[row] = red[8] + red[9] + red[10] + red[11];
}

// ---------------- yat GEMM (pipelined, 3-buffer distance-2) -----------------
constexpr int M_QKV = 0, M_AO = 1, M_PROJ = 4;

struct GemmArgs {
  const unsigned short* A; const unsigned short* Bt;
  const float* arow2; const float* wcol2; const float* bias; const float* alpha;
  int N;
  const float* rope;                                    // QKV
  unsigned short* qo; unsigned short* ko; unsigned short* vo;  // QKV
  const float* xf; float* xo;                           // AO: residual in/out (f32)
  const float* xo_in; float* outf;                      // PROJ: residual in, f32 out
};

template <int MODE, int NI>
__global__ __launch_bounds__(256, 2) void k_gemm(GemmArgs p) {
  constexpr int K = NI * 32;
  __shared__ __align__(16) unsigned short As[3][4096];
  __shared__ __align__(16) unsigned short Bs[3][4096];
  const int tid = threadIdx.x, wave = tid >> 6, lane = tid & 63;
  const int quad = lane >> 4, l = lane & 15;
  const int bm = blockIdx.x * 128, bn = blockIdx.y * 128;
  const int wm = (wave & 1) * 64, wn = (wave >> 1) * 64;
  const f32x4 fzero = {0.f, 0.f, 0.f, 0.f};
  f32x4 acc[4][4];
  #pragma unroll
  for (int i = 0; i < 4; ++i)
    #pragma unroll
    for (int j = 0; j < 4; ++j) acc[i][j] = fzero;
  const int sw = (l >> 1) & 3;

  auto stage = [&](int s, int k0) {
    #pragma unroll
    for (int it = 0; it < 2; ++it) {
      int ci = tid + it * 256;
      int r = ci >> 2;
      int c = (ci & 3) ^ ((r >> 1) & 3);
      async16(p.A + (long)(bm + r) * K + k0 + c * 8, &As[s][ci * 8]);
      async16(p.Bt + (long)(bn + r) * K + k0 + c * 8, &Bs[s][ci * 8]);
    }
  };
  auto compute = [&](int s) {
    bf16x8 af[4], bfv[4];
    #pragma unroll
    for (int mi = 0; mi < 4; ++mi)
      af[mi] = *(const bf16x8*)&As[s][(wm + mi * 16 + l) * 32 + ((quad ^ sw) * 8)];
    #pragma unroll
    for (int ni = 0; ni < 4; ++ni)
      bfv[ni] = *(const bf16x8*)&Bs[s][(wn + ni * 16 + l) * 32 + ((quad ^ sw) * 8)];
    #pragma unroll
    for (int mi = 0; mi < 4; ++mi)
      #pragma unroll
      for (int ni = 0; ni < 4; ++ni)
        acc[mi][ni] = __builtin_amdgcn_mfma_f32_16x16x32_bf16(af[mi], bfv[ni], acc[mi][ni], 0, 0, 0);
  };
  auto iter = [&](int s, int i) {
    if (i + 1 >= NI) { asm volatile("s_waitcnt vmcnt(0)" ::: "memory"); }
    else             { asm volatile("s_waitcnt vmcnt(4)" ::: "memory"); }
    __builtin_amdgcn_s_barrier();
    asm volatile("" ::: "memory");
    if (i + 2 < NI) stage(s == 0 ? 2 : s - 1, (i + 2) * 32);
    compute(s);
  };

  stage(0, 0);
  stage(1, 32);
  int i = 0;
  while (i < NI) {          // NI % 3 == 0
    iter(0, i); ++i;
    iter(1, i); ++i;
    iter(2, i); ++i;
  }

  // epilogue: v = ((y^2)/(||a||^2+||w||^2-2y+eps) + bias) * (sqrt(N)/log1p(N))^alpha
  const float al = p.alpha[0];
  const float nn = (float)p.N;
  const float ys = powf(sqrtf(nn) / log1pf(nn), al);
  #pragma unroll
  for (int ni = 0; ni < 4; ++ni) {
    const int j = bn + wn + ni * 16 + l;
    const float w2 = p.wcol2[j];
    const float bj = p.bias[j];
    int s3 = 0, hh = 0, dd = 0;
    if constexpr (MODE == M_QKV) { s3 = j / 768; int rem = j - s3 * 768; hh = rem >> 6; dd = rem & 63; }
    #pragma unroll
    for (int mi = 0; mi < 4; ++mi) {
      const int i0 = bm + wm + mi * 16 + quad * 4;
      float vv[4];
      #pragma unroll
      for (int rg = 0; rg < 4; ++rg) {
        const int ii = i0 + rg;
        const float y = acc[mi][ni][rg];
        const float dist = p.arow2[ii] + w2 - 2.f * y + 1e-6f;
        vv[rg] = (y * y / dist + bj) * ys;
      }
      if constexpr (MODE == M_QKV) {
        int b = i0 >> 10, t0 = i0 & 1023;
        if (s3 == 2) {
          us4 pk = {f2bf(vv[0]), f2bf(vv[1]), f2bf(vv[2]), f2bf(vv[3])};
          *(us4*)&p.vo[((long)(b * 12 + hh) * 64 + dd) * 1024 + t0] = pk;    // V^T (B,H,D,T)
        } else {
          unsigned short* dst = (s3 == 0) ? p.qo : p.ko;                     // (B,H,T,D)
          #pragma unroll
          for (int rg = 0; rg < 4; ++rg) {
            float ro = p.rope[(t0 + rg) * 64 + dd];
            dst[((long)(b * 12 + hh) * 1024 + t0 + rg) * 64 + dd] = f2bf(vv[rg] * ro);
          }
        }
      } else if constexpr (MODE == M_AO) {
        #pragma unroll
        for (int rg = 0; rg < 4; ++rg) {
          long idx = (long)(i0 + rg) * 768 + j;
          p.xo[idx] = p.xf[idx] + vv[rg];
        }
      } else {  // M_PROJ -> f32 output
        #pragma unroll
        for (int rg = 0; rg < 4; ++rg) {
          long idx = (long)(i0 + rg) * 768 + j;
          p.outf[idx] = p.xo_in[idx] + vv[rg];
        }
      }
    }
  }
}

// ---------------- merged FC+GATE yat GEMM (2-buffer pipeline) ---------------
struct MlpArgs {
  const unsigned short* A; const unsigned short* Bf; const unsigned short* Bg;
  const float* arow2; const float* w2f; const float* w2g;
  const float* bf; const float* bg; const float* af_; const float* ag_;
  unsigned short* mlp; float* mrow2;
};

__global__ __launch_bounds__(256, 2) void k_mlp(MlpArgs p) {
  constexpr int NI = 24, K = 768;
  __shared__ __align__(16) unsigned short As[2][4096];
  __shared__ __align__(16) unsigned short Bfs[2][4096];
  __shared__ __align__(16) unsigned short Bgs[2][4096];
  const int tid = threadIdx.x, wave = tid >> 6, lane = tid & 63;
  const int quad = lane >> 4, l = lane & 15;
  const int bm = blockIdx.x * 128, bn = blockIdx.y * 128;
  const int wm = (wave & 1) * 64, wn = (wave >> 1) * 64;
  const f32x4 fzero = {0.f, 0.f, 0.f, 0.f};
  f32x4 accf[4][4], accg[4][4];
  #pragma unroll
  for (int i = 0; i < 4; ++i)
    #pragma unroll
    for (int j = 0; j < 4; ++j) { accf[i][j] = fzero; accg[i][j] = fzero; }
  const int sw = (l >> 1) & 3;

  auto stage = [&](int s, int k0) {
    #pragma unroll
    for (int it = 0; it < 2; ++it) {
      int ci = tid + it * 256;
      int r = ci >> 2;
      int c = (ci & 3) ^ ((r >> 1) & 3);
      async16(p.A  + (long)(bm + r) * K + k0 + c * 8, &As[s][ci * 8]);
      async16(p.Bf + (long)(bn + r) * K + k0 + c * 8, &Bfs[s][ci * 8]);
      async16(p.Bg + (long)(bn + r) * K + k0 + c * 8, &Bgs[s][ci * 8]);
    }
  };

  stage(0, 0);
  for (int i = 0; i < NI; ++i) {
    int s = i & 1;
    asm volatile("s_waitcnt vmcnt(0)" ::: "memory");
    __builtin_amdgcn_s_barrier();
    asm volatile("" ::: "memory");
    if (i + 1 < NI) stage(s ^ 1, (i + 1) * 32);
    bf16x8 af[4], bff[4], bfg[4];
    #pragma unroll
    for (int mi = 0; mi < 4; ++mi)
      af[mi] = *(const bf16x8*)&As[s][(wm + mi * 16 + l) * 32 + ((quad ^ sw) * 8)];
    #pragma unroll
    for (int ni = 0; ni < 4; ++ni) {
      bff[ni] = *(const bf16x8*)&Bfs[s][(wn + ni * 16 + l) * 32 + ((quad ^ sw) * 8)];
      bfg[ni] = *(const bf16x8*)&Bgs[s][(wn + ni * 16 + l) * 32 + ((quad ^ sw) * 8)];
    }
    #pragma unroll
    for (int mi = 0; mi < 4; ++mi)
      #pragma unroll
      for (int ni = 0; ni < 4; ++ni) {
        accf[mi][ni] = __builtin_amdgcn_mfma_f32_16x16x32_bf16(af[mi], bff[ni], accf[mi][ni], 0, 0, 0);
        accg[mi][ni] = __builtin_amdgcn_mfma_f32_16x16x32_bf16(af[mi], bfg[ni], accg[mi][ni], 0, 0, 0);
      }
  }

  const float ysf = powf(sqrtf(3072.f) / log1pf(3072.f), p.af_[0]);
  const float ysg = powf(sqrtf(3072.f) / log1pf(3072.f), p.ag_[0]);
  float w2f[4], w2g[4], bjf[4], bjg[4]; int js[4];
  #pragma unroll
  for (int ni = 0; ni < 4; ++ni) {
    int j = bn + wn + ni * 16 + l;
    js[ni] = j; w2f[ni] = p.w2f[j]; w2g[ni] = p.w2g[j]; bjf[ni] = p.bf[j]; bjg[ni] = p.bg[j];
  }
  #pragma unroll
  for (int mi = 0; mi < 4; ++mi) {
    #pragma unroll
    for (int rg = 0; rg < 4; ++rg) {
      const int ii = bm + wm + mi * 16 + quad * 4 + rg;
      const float a2 = p.arow2[ii];
      float rsum = 0.f;
      #pragma unroll
      for (int ni = 0; ni < 4; ++ni) {
        float yf = accf[mi][ni][rg];
        float gate = (yf * yf / (a2 + w2f[ni] - 2.f * yf + 1e-6f) + bjf[ni]) * ysf;
        float yg = accg[mi][ni][rg];
        float u  = (yg * yg / (a2 + w2g[ni] - 2.f * yg + 1e-6f) + bjg[ni]) * ysg;
        float out = gelu_t(u) * gate;
        p.mlp[(long)ii * 3072 + js[ni]] = f2bf(out);
        rsum += out * out;
      }
      #pragma unroll
      for (int o = 8; o; o >>= 1) rsum += __shfl_xor(rsum, o);
      if (l == 0) atomicAdd(&p.mrow2[ii], rsum);
    }
  }
}

// ---------------- flash attention: 64-row Q tiles, causal -------------------
__global__ __launch_bounds__(256) void k_attn(const unsigned short* __restrict__ qb,
    const unsigned short* __restrict__ kb, const unsigned short* __restrict__ vb,
    unsigned short* __restrict__ ob, float* __restrict__ orow2) {
  __shared__ __align__(16) unsigned short Qs[64 * 64];
  __shared__ __align__(16) unsigned short Ks[64 * 64];
  __shared__ __align__(16) unsigned short Vs[64 * 64];
  __shared__ __align__(16) unsigned short Ps[4 * 16 * 64];
  const int tid = threadIdx.x, wave = tid >> 6, lane = tid & 63;
  const int quad = lane >> 4, l = lane & 15;
  const int qt = blockIdx.x, bh = blockIdx.y;
  const int b = bh / 12, hh = bh % 12;
  const int q0 = qt * 64;
  const f32x4 fzero = {0.f, 0.f, 0.f, 0.f};

  const unsigned short* qg = qb + ((long)bh * 1024 + q0) * 64;
  #pragma unroll
  for (int it = 0; it < 2; ++it) {
    int ci = tid + it * 256;
    int r = ci >> 3;
    int c = (ci & 7) ^ (r & 7);
    async16(qg + (long)r * 64 + c * 8, &Qs[ci * 8]);
  }
  __builtin_amdgcn_s_waitcnt(0);
  __syncthreads();
  bf16x8 aq[2];
  #pragma unroll
  for (int ks = 0; ks < 2; ++ks)
    aq[ks] = *(const bf16x8*)&Qs[(wave * 16 + l) * 64 + (((ks * 4 + quad) ^ (l & 7)) * 8)];

  f32x4 O[4];
  float mi_[4], li[4];
  #pragma unroll
  for (int f = 0; f < 4; ++f) O[f] = fzero;
  #pragma unroll
  for (int r = 0; r < 4; ++r) { mi_[r] = -1e30f; li[r] = 0.f; }

  for (int jt = 0; jt <= qt; ++jt) {
    __syncthreads();
    const unsigned short* kg = kb + ((long)bh * 1024 + jt * 64) * 64;
    const unsigned short* vg = vb + (long)bh * 64 * 1024 + jt * 64;
    #pragma unroll
    for (int it = 0; it < 2; ++it) {
      int ci = tid + it * 256;
      int r = ci >> 3;
      int c = (ci & 7) ^ (r & 7);
      async16(kg + (long)r * 64 + c * 8, &Ks[ci * 8]);
      async16(vg + (long)r * 1024 + c * 8, &Vs[ci * 8]);
    }
    __builtin_amdgcn_s_waitcnt(0);
    __syncthreads();

    f32x4 S[4];
    #pragma unroll
    for (int f = 0; f < 4; ++f) S[f] = fzero;
    #pragma unroll
    for (int ks = 0; ks < 2; ++ks) {
      #pragma unroll
      for (int f = 0; f < 4; ++f) {
        bf16x8 bk = *(const bf16x8*)&Ks[(f * 16 + l) * 64 + (((ks * 4 + quad) ^ (l & 7)) * 8)];
        S[f] = __builtin_amdgcn_mfma_f32_16x16x32_bf16(aq[ks], bk, S[f], 0, 0, 0);
      }
    }
    const bool diag = (jt == qt);
    #pragma unroll
    for (int f = 0; f < 4; ++f)
      #pragma unroll
      for (int r = 0; r < 4; ++r) {
        float v = S[f][r] * 0.125f;
        if (diag && (f * 16 + l > wave * 16 + quad * 4 + r)) v = -1e30f;
        S[f][r] = v;
      }
    #pragma unroll
    for (int r = 0; r < 4; ++r) {
      float mx = fmaxf(fmaxf(S[0][r], S[1][r]), fmaxf(S[2][r], S[3][r]));
      #pragma unroll
      for (int o = 8; o; o >>= 1) mx = fmaxf(mx, __shfl_xor(mx, o));
      float mnew = fmaxf(mi_[r], mx);
      float alr = __expf(mi_[r] - mnew);
      float sum = 0.f;
      #pragma unroll
      for (int f = 0; f < 4; ++f) {
        float e = __expf(S[f][r] - mnew);
        S[f][r] = e;
        sum += e;
      }
      #pragma unroll
      for (int o = 8; o; o >>= 1) sum += __shfl_xor(sum, o);
      li[r] = li[r] * alr + sum;
      #pragma unroll
      for (int f = 0; f < 4; ++f) O[f][r] *= alr;
      mi_[r] = mnew;
    }
    #pragma unroll
    for (int f = 0; f < 4; ++f)
      #pragma unroll
      for (int r = 0; r < 4; ++r) {
        int i = quad * 4 + r;
        int j = f * 16 + l;
        int pch = (j >> 3) ^ (i & 7);
        Ps[wave * 1024 + i * 64 + pch * 8 + (j & 7)] = f2bf(S[f][r]);
      }
    #pragma unroll
    for (int ks = 0; ks < 2; ++ks) {
      bf16x8 ap = *(const bf16x8*)&Ps[wave * 1024 + l * 64 + (((ks * 4 + quad) ^ (l & 7)) * 8)];
      #pragma unroll
      for (int f = 0; f < 4; ++f) {
        bf16x8 bv = *(const bf16x8*)&Vs[(f * 16 + l) * 64 + (((ks * 4 + quad) ^ (l & 7)) * 8)];
        O[f] = __builtin_amdgcn_mfma_f32_16x16x32_bf16(ap, bv, O[f], 0, 0, 0);
      }
    }
  }
  #pragma unroll
  for (int f = 0; f < 4; ++f)
    #pragma unroll
    for (int r = 0; r < 4; ++r) {
      int t = q0 + wave * 16 + quad * 4 + r;
      int dd = f * 16 + l;
      float v = O[f][r] / li[r];
      ob[((long)(b * 1024 + t) * 12 + hh) * 64 + dd] = f2bf(v);  // (B,T,H,D)
    }
  // fused row-sumsq partial (this head's 64 cols) -> orow2
  #pragma unroll
  for (int r = 0; r < 4; ++r) {
    float rsum = 0.f;
    #pragma unroll
    for (int f = 0; f < 4; ++f) { float v = O[f][r] / li[r]; rsum += v * v; }
    #pragma unroll
    for (int o = 8; o; o >>= 1) rsum += __shfl_xor(rsum, o);
    if (l == 0) {
      int t = q0 + wave * 16 + quad * 4 + r;
      atomicAdd(&orow2[b * 1024 + t], rsum);
    }
  }
}

// ---------------- host ------------------------------------------------------
extern "C" void kernel_launch(void* const* d_in, const int* in_sizes, int n_in,
                              void* d_out, int out_size, void* d_ws, size_t ws_size,
                              hipStream_t stream) {
  (void)in_sizes; (void)n_in; (void)out_size;
  char* w = (char*)d_ws;
  size_t off = 0;
  auto alloc = [&](size_t bytes) -> void* {
    void* p = w + off;
    off = (off + bytes + 255) & ~(size_t)255;
    return p;
  };
  float* rope            = (float*)alloc(65536 * 4);
  unsigned short* wtqkv  = (unsigned short*)alloc((size_t)2304 * 768 * 2);
  unsigned short* wtao   = (unsigned short*)alloc((size_t)768 * 768 * 2);
  unsigned short* wtfc   = (unsigned short*)alloc((size_t)3072 * 768 * 2);
  unsigned short* wtgate = (unsigned short*)alloc((size_t)3072 * 768 * 2);
  unsigned short* wtproj = (unsigned short*)alloc((size_t)768 * 3072 * 2);
  float* zeroed          = (float*)alloc(14080 * 4);   // wcol2(9984) + orow2(2048) + mrow2(2048)
  unsigned short* h1     = (unsigned short*)alloc((size_t)2048 * 768 * 2);
  float* hrow1           = (float*)alloc(2048 * 4);
  unsigned short* qbuf   = (unsigned short*)alloc((size_t)2048 * 768 * 2);
  unsigned short* kbuf   = (unsigned short*)alloc((size_t)2048 * 768 * 2);
  unsigned short* vbuf   = (unsigned short*)alloc((size_t)2048 * 768 * 2);
  unsigned short* obuf   = (unsigned short*)alloc((size_t)2048 * 768 * 2);
  float* xo              = (float*)alloc((size_t)2048 * 768 * 4);
  unsigned short* h2     = (unsigned short*)alloc((size_t)2048 * 768 * 2);
  float* hrow2           = (float*)alloc(2048 * 4);
  unsigned short* mlp    = (unsigned short*)alloc((size_t)2048 * 3072 * 2);
  if (off > ws_size) return;

  float* wcol2  = zeroed;
  float* orow2  = zeroed + 9984;
  float* mrow2  = zeroed + 9984 + 2048;
  float* c_qkv  = wcol2 + 0;
  float* c_ao   = wcol2 + 2304;
  float* c_fc   = wcol2 + 3072;
  float* c_gate = wcol2 + 6144;
  float* c_proj = wcol2 + 9216;

  const float* xin = (const float*)d_in[0];

  hipMemsetAsync(zeroed, 0, 14080 * 4, stream);
  k_rope<<<256, 256, 0, stream>>>(rope);

  k_transpose<<<dim3(72, 24), 256, 0, stream>>>((const float*)d_in[3],  wtqkv,  c_qkv,  2304, 768);
  k_transpose<<<dim3(24, 24), 256, 0, stream>>>((const float*)d_in[6],  wtao,   c_ao,   768,  768);
  k_transpose<<<dim3(96, 24), 256, 0, stream>>>((const float*)d_in[10], wtfc,   c_fc,   3072, 768);
  k_transpose<<<dim3(96, 24), 256, 0, stream>>>((const float*)d_in[13], wtgate, c_gate, 3072, 768);
  k_transpose<<<dim3(24, 96), 256, 0, stream>>>((const float*)d_in[16], wtproj, c_proj, 768,  3072);

  k_ln<<<2048, 256, 0, stream>>>(xin, (const float*)d_in[2], h1, hrow1);

  GemmArgs gq = {};
  gq.A = h1; gq.Bt = wtqkv; gq.arow2 = hrow1; gq.wcol2 = c_qkv;
  gq.bias = (const float*)d_in[4]; gq.alpha = (const float*)d_in[5]; gq.N = 2304;
  gq.rope = rope; gq.qo = qbuf; gq.ko = kbuf; gq.vo = vbuf;
  k_gemm<M_QKV, 24><<<dim3(16, 18), 256, 0, stream>>>(gq);

  k_attn<<<dim3(16, 24), 256, 0, stream>>>(qbuf, kbuf, vbuf, obuf, orow2);

  GemmArgs ga = {};
  ga.A = obuf; ga.Bt = wtao; ga.arow2 = orow2; ga.wcol2 = c_ao;
  ga.bias = (const float*)d_in[7]; ga.alpha = (const float*)d_in[8]; ga.N = 768;
  ga.xf = xin; ga.xo = xo;
  k_gemm<M_AO, 24><<<dim3(16, 6), 256, 0, stream>>>(ga);

  k_ln<<<2048, 256, 0, stream>>>(xo, (const float*)d_in[9], h2, hrow2);

  MlpArgs gm = {};
  gm.A = h2; gm.Bf = wtfc; gm.Bg = wtgate; gm.arow2 = hrow2;
  gm.w2f = c_fc; gm.w2g = c_gate;
  gm.bf = (const float*)d_in[11]; gm.bg = (const float*)d_in[14];
  gm.af_ = (const float*)d_in[12]; gm.ag_ = (const float*)d_in[15];
  gm.mlp = mlp; gm.mrow2 = mrow2;
  k_mlp<<<dim3(16, 24), 256, 0, stream>>>(gm);

  GemmArgs gp = {};
  gp.A = mlp; gp.Bt = wtproj; gp.arow2 = mrow2; gp.wcol2 = c_proj;
  gp.bias = (const float*)d_in[17]; gp.alpha = (const float*)d_in[18]; gp.N = 768;
  gp.xo_in = xo; gp.outf = (float*)d_out;
  k_gemm<M_PROJ, 96><<<dim3(16, 6), 256, 0, stream>>>(gp);
}

// Round 4
// 311.442 us; speedup vs baseline: 1.3245x; 1.1501x over previous
//
#include <hip/hip_runtime.h>
#include <cstdint>

#define DEVFN static __device__ __forceinline__

typedef __bf16 bf16x8 __attribute__((ext_vector_type(8)));
typedef float f32x4 __attribute__((ext_vector_type(4)));
typedef unsigned short us4 __attribute__((ext_vector_type(4)));

DEVFN unsigned short f2bf(float f) {
  unsigned u = __float_as_uint(f);
  u += 0x7fffu + ((u >> 16) & 1u);           // round-to-nearest-even
  return (unsigned short)(u >> 16);
}
DEVFN float bf2f(unsigned short h) { return __uint_as_float(((unsigned)h) << 16); }
DEVFN void async16(const void* g, void* l) {
  __builtin_amdgcn_global_load_lds((__attribute__((address_space(1))) const void*)g,
                                   (__attribute__((address_space(3))) void*)l, 16, 0, 0);
}
DEVFN float gelu_t(float u) {
  return 0.5f * u * (1.f + tanhf(0.7978845608028654f * (u + 0.044715f * u * u * u)));
}

// ---------------- rope table ------------------------------------------------
__global__ __launch_bounds__(256) void k_rope(float* __restrict__ rope) {
  int g = blockIdx.x * 256 + threadIdx.x;
  int t = g >> 6, dd = g & 63, i = dd & 31;
  float fr = __expf(-0.2878231366242558f * (float)i);   // ln(1e4)/32
  float ang = (float)t * fr;
  rope[g] = (dd < 32) ? cosf(ang) : sinf(ang);
}

// ---------------- weight transpose (K x N f32 -> N x K bf16) + col sq-norms -
__global__ __launch_bounds__(256) void k_transpose(const float* __restrict__ W,
    unsigned short* __restrict__ Wt, float* __restrict__ cn, int N, int K) {
  __shared__ float tile[32][33];
  __shared__ float part[8][32];
  int tx = threadIdx.x & 31, ty = threadIdx.x >> 5;
  int tn = blockIdx.x, tk = blockIdx.y;
  float acc = 0.f;
  #pragma unroll
  for (int j = 0; j < 4; ++j) {
    int r = ty + j * 8;
    float v = W[(long)(tk * 32 + r) * N + tn * 32 + tx];
    tile[r][tx] = v;
    acc += v * v;
  }
  part[ty][tx] = acc;
  __syncthreads();
  #pragma unroll
  for (int j = 0; j < 4; ++j) {
    int rr = ty + j * 8;
    Wt[(long)(tn * 32 + rr) * K + tk * 32 + tx] = f2bf(tile[tx][rr]);
  }
  if (ty == 0) {
    float s = part[0][tx];
    #pragma unroll
    for (int jj = 1; jj < 8; ++jj) s += part[jj][tx];
    atomicAdd(&cn[tn * 32 + tx], s);
  }
}

// ---------------- layernorm (f32 in) -> bf16 h + row sum(h^2) ---------------
__global__ __launch_bounds__(256) void k_ln(const float* __restrict__ x,
    const float* __restrict__ g, unsigned short* __restrict__ h, float* __restrict__ row2) {
  int row = blockIdx.x, tid = threadIdx.x;
  const float* xr = x + (long)row * 768;
  float v0 = xr[tid], v1 = xr[tid + 256], v2 = xr[tid + 512];
  float s = v0 + v1 + v2;
  float ss = v0 * v0 + v1 * v1 + v2 * v2;
  #pragma unroll
  for (int o = 32; o; o >>= 1) { s += __shfl_xor(s, o); ss += __shfl_xor(ss, o); }
  __shared__ float red[12];
  int wv = tid >> 6;
  if ((tid & 63) == 0) { red[wv] = s; red[wv + 4] = ss; }
  __syncthreads();
  s = red[0] + red[1] + red[2] + red[3];
  ss = red[4] + red[5] + red[6] + red[7];
  float mu = s * (1.f / 768.f);
  float var = ss * (1.f / 768.f) - mu * mu;
  float rs = rsqrtf(var + 1e-6f);
  float h0 = (v0 - mu) * rs * g[tid];
  float h1 = (v1 - mu) * rs * g[tid + 256];
  float h2 = (v2 - mu) * rs * g[tid + 512];
  unsigned short* hr = h + (long)row * 768;
  hr[tid] = f2bf(h0); hr[tid + 256] = f2bf(h1); hr[tid + 512] = f2bf(h2);
  float p = h0 * h0 + h1 * h1 + h2 * h2;
  #pragma unroll
  for (int o = 32; o; o >>= 1) p += __shfl_xor(p, o);
  if ((tid & 63) == 0) red[8 + wv] = p;
  __syncthreads();
  if (tid == 0) row2[row] = red[8] + red[9] + red[10] + red[11];
}

// ---------------- yat GEMM: 64x128 tile, 3-buffer distance-2 pipeline -------
constexpr int M_QKV = 0, M_AO = 1, M_PART = 2;

struct GemmArgs {
  const unsigned short* A; const unsigned short* Bt;
  const float* arow2; const float* wcol2; const float* bias; const float* alpha;
  int N; int ks;                                        // ks = row stride in K dim
  const float* rope;                                    // QKV
  unsigned short* qo; unsigned short* ko; unsigned short* vo;  // QKV
  const float* xf; float* xo;                           // AO: residual in/out (f32)
  float* part;                                          // PART: f32 slab base
};

template <int MODE, int NI>
__global__ __launch_bounds__(256, 4) void k_gemm(GemmArgs p) {
  __shared__ __align__(16) unsigned short As[3][2048];   // 64 x 32
  __shared__ __align__(16) unsigned short Bs[3][4096];   // 128 x 32
  const int tid = threadIdx.x, wave = tid >> 6, lane = tid & 63;
  const int quad = lane >> 4, l = lane & 15;
  const int bm = blockIdx.x * 64, bn = blockIdx.y * 128;
  const int kb = (MODE == M_PART) ? (int)blockIdx.z * (NI * 32) : 0;
  const int ks = p.ks;
  const int wm = (wave & 1) * 32, wn = (wave >> 1) * 64;
  const f32x4 fzero = {0.f, 0.f, 0.f, 0.f};
  f32x4 acc[2][4];
  #pragma unroll
  for (int i = 0; i < 2; ++i)
    #pragma unroll
    for (int j = 0; j < 4; ++j) acc[i][j] = fzero;
  const int sw = (l >> 1) & 3;

  auto stage = [&](int s, int k0) {
    {
      int ci = tid;
      int r = ci >> 2;
      int c = (ci & 3) ^ ((r >> 1) & 3);
      async16(p.A + (long)(bm + r) * ks + kb + k0 + c * 8, &As[s][ci * 8]);
    }
    #pragma unroll
    for (int it = 0; it < 2; ++it) {
      int ci = tid + it * 256;
      int r = ci >> 2;
      int c = (ci & 3) ^ ((r >> 1) & 3);
      async16(p.Bt + (long)(bn + r) * ks + kb + k0 + c * 8, &Bs[s][ci * 8]);
    }
  };
  auto compute = [&](int s) {
    bf16x8 af[2], bfv[4];
    #pragma unroll
    for (int mi = 0; mi < 2; ++mi)
      af[mi] = *(const bf16x8*)&As[s][(wm + mi * 16 + l) * 32 + ((quad ^ sw) * 8)];
    #pragma unroll
    for (int ni = 0; ni < 4; ++ni)
      bfv[ni] = *(const bf16x8*)&Bs[s][(wn + ni * 16 + l) * 32 + ((quad ^ sw) * 8)];
    #pragma unroll
    for (int mi = 0; mi < 2; ++mi)
      #pragma unroll
      for (int ni = 0; ni < 4; ++ni)
        acc[mi][ni] = __builtin_amdgcn_mfma_f32_16x16x32_bf16(af[mi], bfv[ni], acc[mi][ni], 0, 0, 0);
  };
  auto iter = [&](int s, int i) {
    if (i + 1 >= NI) { asm volatile("s_waitcnt vmcnt(0)" ::: "memory"); }
    else             { asm volatile("s_waitcnt vmcnt(3)" ::: "memory"); }
    __builtin_amdgcn_s_barrier();
    asm volatile("" ::: "memory");
    if (i + 2 < NI) stage(s == 0 ? 2 : s - 1, (i + 2) * 32);
    compute(s);
  };

  stage(0, 0);
  stage(1, 32);
  int i = 0;
  while (i < NI) {          // NI % 3 == 0
    iter(0, i); ++i;
    iter(1, i); ++i;
    iter(2, i); ++i;
  }

  if constexpr (MODE == M_PART) {
    float* slab = p.part + (long)blockIdx.z * (2048 * 768);
    #pragma unroll
    for (int ni = 0; ni < 4; ++ni) {
      const int j = bn + wn + ni * 16 + l;
      #pragma unroll
      for (int mi = 0; mi < 2; ++mi) {
        const int i0 = bm + wm + mi * 16 + quad * 4;
        #pragma unroll
        for (int rg = 0; rg < 4; ++rg)
          slab[(long)(i0 + rg) * 768 + j] = acc[mi][ni][rg];
      }
    }
  } else {
    const float al = p.alpha[0];
    const float nn = (float)p.N;
    const float ys = powf(sqrtf(nn) / log1pf(nn), al);
    #pragma unroll
    for (int ni = 0; ni < 4; ++ni) {
      const int j = bn + wn + ni * 16 + l;
      const float w2 = p.wcol2[j];
      const float bj = p.bias[j];
      int s3 = 0, hh = 0, dd = 0;
      if constexpr (MODE == M_QKV) { s3 = j / 768; int rem = j - s3 * 768; hh = rem >> 6; dd = rem & 63; }
      #pragma unroll
      for (int mi = 0; mi < 2; ++mi) {
        const int i0 = bm + wm + mi * 16 + quad * 4;
        float vv[4];
        #pragma unroll
        for (int rg = 0; rg < 4; ++rg) {
          const float y = acc[mi][ni][rg];
          const float dist = p.arow2[i0 + rg] + w2 - 2.f * y + 1e-6f;
          vv[rg] = (y * y / dist + bj) * ys;
        }
        if constexpr (MODE == M_QKV) {
          int b = i0 >> 10, t0 = i0 & 1023;
          if (s3 == 2) {
            us4 pk = {f2bf(vv[0]), f2bf(vv[1]), f2bf(vv[2]), f2bf(vv[3])};
            *(us4*)&p.vo[((long)(b * 12 + hh) * 64 + dd) * 1024 + t0] = pk;    // V^T (B,H,D,T)
          } else {
            unsigned short* dst = (s3 == 0) ? p.qo : p.ko;                     // (B,H,T,D)
            #pragma unroll
            for (int rg = 0; rg < 4; ++rg) {
              float ro = p.rope[(t0 + rg) * 64 + dd];
              dst[((long)(b * 12 + hh) * 1024 + t0 + rg) * 64 + dd] = f2bf(vv[rg] * ro);
            }
          }
        } else {  // M_AO
          #pragma unroll
          for (int rg = 0; rg < 4; ++rg) {
            long idx = (long)(i0 + rg) * 768 + j;
            p.xo[idx] = p.xf[idx] + vv[rg];
          }
        }
      }
    }
  }
}

// ---------------- PROJ reduce + yat epilogue + residual ---------------------
struct EpiArgs {
  const float* slab; const float* arow2; const float* wcol2;
  const float* bias; const float* alpha; const float* xo; float* outf;
};
__global__ __launch_bounds__(256) void k_proj_epi(EpiArgs p) {
  int g = blockIdx.x * 256 + threadIdx.x;   // 393216 = 2048*768/4
  int i = g / 192, jv = (g - i * 192) * 4;
  long base = (long)i * 768 + jv;
  f32x4 y = *(const f32x4*)(p.slab + base);
  y += *(const f32x4*)(p.slab + 1572864 + base);
  y += *(const f32x4*)(p.slab + 2 * 1572864 + base);
  y += *(const f32x4*)(p.slab + 3 * 1572864 + base);
  const float a2 = p.arow2[i];
  const float ys = powf(sqrtf(768.f) / log1pf(768.f), p.alpha[0]);
  f32x4 xo4 = *(const f32x4*)(p.xo + base);
  f32x4 out;
  #pragma unroll
  for (int c = 0; c < 4; ++c) {
    float yy = y[c];
    float dist = a2 + p.wcol2[jv + c] - 2.f * yy + 1e-6f;
    out[c] = xo4[c] + (yy * yy / dist + p.bias[jv + c]) * ys;
  }
  *(f32x4*)(p.outf + base) = out;
}

// ---------------- merged FC+GATE yat GEMM (64x128, 3-buffer) ----------------
struct MlpArgs {
  const unsigned short* A; const unsigned short* Bf; const unsigned short* Bg;
  const float* arow2; const float* w2f; const float* w2g;
  const float* bf; const float* bg; const float* af_; const float* ag_;
  unsigned short* mlp; float* mrow2;
};

__global__ __launch_bounds__(256, 2) void k_mlp(MlpArgs p) {
  constexpr int NI = 24, K = 768;
  __shared__ __align__(16) unsigned short As[3][2048];
  __shared__ __align__(16) unsigned short Bfs[3][4096];
  __shared__ __align__(16) unsigned short Bgs[3][4096];
  const int tid = threadIdx.x, wave = tid >> 6, lane = tid & 63;
  const int quad = lane >> 4, l = lane & 15;
  const int bm = blockIdx.x * 64, bn = blockIdx.y * 128;
  const int wm = (wave & 1) * 32, wn = (wave >> 1) * 64;
  const f32x4 fzero = {0.f, 0.f, 0.f, 0.f};
  f32x4 accf[2][4], accg[2][4];
  #pragma unroll
  for (int i = 0; i < 2; ++i)
    #pragma unroll
    for (int j = 0; j < 4; ++j) { accf[i][j] = fzero; accg[i][j] = fzero; }
  const int sw = (l >> 1) & 3;

  auto stage = [&](int s, int k0) {
    {
      int ci = tid;
      int r = ci >> 2;
      int c = (ci & 3) ^ ((r >> 1) & 3);
      async16(p.A + (long)(bm + r) * K + k0 + c * 8, &As[s][ci * 8]);
    }
    #pragma unroll
    for (int it = 0; it < 2; ++it) {
      int ci = tid + it * 256;
      int r = ci >> 2;
      int c = (ci & 3) ^ ((r >> 1) & 3);
      async16(p.Bf + (long)(bn + r) * K + k0 + c * 8, &Bfs[s][ci * 8]);
      async16(p.Bg + (long)(bn + r) * K + k0 + c * 8, &Bgs[s][ci * 8]);
    }
  };
  auto compute = [&](int s) {
    bf16x8 af[2], bff[4], bfg[4];
    #pragma unroll
    for (int mi = 0; mi < 2; ++mi)
      af[mi] = *(const bf16x8*)&As[s][(wm + mi * 16 + l) * 32 + ((quad ^ sw) * 8)];
    #pragma unroll
    for (int ni = 0; ni < 4; ++ni) {
      bff[ni] = *(const bf16x8*)&Bfs[s][(wn + ni * 16 + l) * 32 + ((quad ^ sw) * 8)];
      bfg[ni] = *(const bf16x8*)&Bgs[s][(wn + ni * 16 + l) * 32 + ((quad ^ sw) * 8)];
    }
    #pragma unroll
    for (int mi = 0; mi < 2; ++mi)
      #pragma unroll
      for (int ni = 0; ni < 4; ++ni) {
        accf[mi][ni] = __builtin_amdgcn_mfma_f32_16x16x32_bf16(af[mi], bff[ni], accf[mi][ni], 0, 0, 0);
        accg[mi][ni] = __builtin_amdgcn_mfma_f32_16x16x32_bf16(af[mi], bfg[ni], accg[mi][ni], 0, 0, 0);
      }
  };
  auto iter = [&](int s, int i) {
    if (i + 1 >= NI) { asm volatile("s_waitcnt vmcnt(0)" ::: "memory"); }
    else             { asm volatile("s_waitcnt vmcnt(5)" ::: "memory"); }
    __builtin_amdgcn_s_barrier();
    asm volatile("" ::: "memory");
    if (i + 2 < NI) stage(s == 0 ? 2 : s - 1, (i + 2) * 32);
    compute(s);
  };

  stage(0, 0);
  stage(1, 32);
  int i = 0;
  while (i < NI) {
    iter(0, i); ++i;
    iter(1, i); ++i;
    iter(2, i); ++i;
  }

  const float ysf = powf(sqrtf(3072.f) / log1pf(3072.f), p.af_[0]);
  const float ysg = powf(sqrtf(3072.f) / log1pf(3072.f), p.ag_[0]);
  float w2f[4], w2g[4], bjf[4], bjg[4]; int js[4];
  #pragma unroll
  for (int ni = 0; ni < 4; ++ni) {
    int j = bn + wn + ni * 16 + l;
    js[ni] = j; w2f[ni] = p.w2f[j]; w2g[ni] = p.w2g[j]; bjf[ni] = p.bf[j]; bjg[ni] = p.bg[j];
  }
  #pragma unroll
  for (int mi = 0; mi < 2; ++mi) {
    #pragma unroll
    for (int rg = 0; rg < 4; ++rg) {
      const int ii = bm + wm + mi * 16 + quad * 4 + rg;
      const float a2 = p.arow2[ii];
      float rsum = 0.f;
      #pragma unroll
      for (int ni = 0; ni < 4; ++ni) {
        float yf = accf[mi][ni][rg];
        float gate = (yf * yf / (a2 + w2f[ni] - 2.f * yf + 1e-6f) + bjf[ni]) * ysf;
        float yg = accg[mi][ni][rg];
        float u  = (yg * yg / (a2 + w2g[ni] - 2.f * yg + 1e-6f) + bjg[ni]) * ysg;
        float out = gelu_t(u) * gate;
        p.mlp[(long)ii * 3072 + js[ni]] = f2bf(out);
        rsum += out * out;
      }
      #pragma unroll
      for (int o = 8; o; o >>= 1) rsum += __shfl_xor(rsum, o);
      if (l == 0) atomicAdd(&p.mrow2[ii], rsum);
    }
  }
}

// ---------------- flash attention: 64-row Q tiles, causal -------------------
__global__ __launch_bounds__(256) void k_attn(const unsigned short* __restrict__ qb,
    const unsigned short* __restrict__ kb, const unsigned short* __restrict__ vb,
    unsigned short* __restrict__ ob, float* __restrict__ orow2) {
  __shared__ __align__(16) unsigned short Qs[64 * 64];
  __shared__ __align__(16) unsigned short Ks[64 * 64];
  __shared__ __align__(16) unsigned short Vs[64 * 64];
  __shared__ __align__(16) unsigned short Ps[4 * 16 * 64];
  const int tid = threadIdx.x, wave = tid >> 6, lane = tid & 63;
  const int quad = lane >> 4, l = lane & 15;
  const int qt = blockIdx.x, bh = blockIdx.y;
  const int b = bh / 12, hh = bh % 12;
  const int q0 = qt * 64;
  const f32x4 fzero = {0.f, 0.f, 0.f, 0.f};

  const unsigned short* qg = qb + ((long)bh * 1024 + q0) * 64;
  #pragma unroll
  for (int it = 0; it < 2; ++it) {
    int ci = tid + it * 256;
    int r = ci >> 3;
    int c = (ci & 7) ^ (r & 7);
    async16(qg + (long)r * 64 + c * 8, &Qs[ci * 8]);
  }
  __builtin_amdgcn_s_waitcnt(0);
  __syncthreads();
  bf16x8 aq[2];
  #pragma unroll
  for (int ks = 0; ks < 2; ++ks)
    aq[ks] = *(const bf16x8*)&Qs[(wave * 16 + l) * 64 + (((ks * 4 + quad) ^ (l & 7)) * 8)];

  f32x4 O[4];
  float mi_[4], li[4];
  #pragma unroll
  for (int f = 0; f < 4; ++f) O[f] = fzero;
  #pragma unroll
  for (int r = 0; r < 4; ++r) { mi_[r] = -1e30f; li[r] = 0.f; }

  for (int jt = 0; jt <= qt; ++jt) {
    __syncthreads();
    const unsigned short* kg = kb + ((long)bh * 1024 + jt * 64) * 64;
    const unsigned short* vg = vb + (long)bh * 64 * 1024 + jt * 64;
    #pragma unroll
    for (int it = 0; it < 2; ++it) {
      int ci = tid + it * 256;
      int r = ci >> 3;
      int c = (ci & 7) ^ (r & 7);
      async16(kg + (long)r * 64 + c * 8, &Ks[ci * 8]);
      async16(vg + (long)r * 1024 + c * 8, &Vs[ci * 8]);
    }
    __builtin_amdgcn_s_waitcnt(0);
    __syncthreads();

    f32x4 S[4];
    #pragma unroll
    for (int f = 0; f < 4; ++f) S[f] = fzero;
    #pragma unroll
    for (int ks = 0; ks < 2; ++ks) {
      #pragma unroll
      for (int f = 0; f < 4; ++f) {
        bf16x8 bk = *(const bf16x8*)&Ks[(f * 16 + l) * 64 + (((ks * 4 + quad) ^ (l & 7)) * 8)];
        S[f] = __builtin_amdgcn_mfma_f32_16x16x32_bf16(aq[ks], bk, S[f], 0, 0, 0);
      }
    }
    const bool diag = (jt == qt);
    #pragma unroll
    for (int f = 0; f < 4; ++f)
      #pragma unroll
      for (int r = 0; r < 4; ++r) {
        float v = S[f][r] * 0.125f;
        if (diag && (f * 16 + l > wave * 16 + quad * 4 + r)) v = -1e30f;
        S[f][r] = v;
      }
    #pragma unroll
    for (int r = 0; r < 4; ++r) {
      float mx = fmaxf(fmaxf(S[0][r], S[1][r]), fmaxf(S[2][r], S[3][r]));
      #pragma unroll
      for (int o = 8; o; o >>= 1) mx = fmaxf(mx, __shfl_xor(mx, o));
      float mnew = fmaxf(mi_[r], mx);
      float alr = __expf(mi_[r] - mnew);
      float sum = 0.f;
      #pragma unroll
      for (int f = 0; f < 4; ++f) {
        float e = __expf(S[f][r] - mnew);
        S[f][r] = e;
        sum += e;
      }
      #pragma unroll
      for (int o = 8; o; o >>= 1) sum += __shfl_xor(sum, o);
      li[r] = li[r] * alr + sum;
      #pragma unroll
      for (int f = 0; f < 4; ++f) O[f][r] *= alr;
      mi_[r] = mnew;
    }
    #pragma unroll
    for (int f = 0; f < 4; ++f)
      #pragma unroll
      for (int r = 0; r < 4; ++r) {
        int i = quad * 4 + r;
        int j = f * 16 + l;
        int pch = (j >> 3) ^ (i & 7);
        Ps[wave * 1024 + i * 64 + pch * 8 + (j & 7)] = f2bf(S[f][r]);
      }
    #pragma unroll
    for (int ks = 0; ks < 2; ++ks) {
      bf16x8 ap = *(const bf16x8*)&Ps[wave * 1024 + l * 64 + (((ks * 4 + quad) ^ (l & 7)) * 8)];
      #pragma unroll
      for (int f = 0; f < 4; ++f) {
        bf16x8 bv = *(const bf16x8*)&Vs[(f * 16 + l) * 64 + (((ks * 4 + quad) ^ (l & 7)) * 8)];
        O[f] = __builtin_amdgcn_mfma_f32_16x16x32_bf16(ap, bv, O[f], 0, 0, 0);
      }
    }
  }
  #pragma unroll
  for (int f = 0; f < 4; ++f)
    #pragma unroll
    for (int r = 0; r < 4; ++r) {
      int t = q0 + wave * 16 + quad * 4 + r;
      int dd = f * 16 + l;
      float v = O[f][r] / li[r];
      ob[((long)(b * 1024 + t) * 12 + hh) * 64 + dd] = f2bf(v);  // (B,T,H,D)
    }
  #pragma unroll
  for (int r = 0; r < 4; ++r) {
    float rsum = 0.f;
    #pragma unroll
    for (int f = 0; f < 4; ++f) { float v = O[f][r] / li[r]; rsum += v * v; }
    #pragma unroll
    for (int o = 8; o; o >>= 1) rsum += __shfl_xor(rsum, o);
    if (l == 0) {
      int t = q0 + wave * 16 + quad * 4 + r;
      atomicAdd(&orow2[b * 1024 + t], rsum);
    }
  }
}

// ---------------- host ------------------------------------------------------
extern "C" void kernel_launch(void* const* d_in, const int* in_sizes, int n_in,
                              void* d_out, int out_size, void* d_ws, size_t ws_size,
                              hipStream_t stream) {
  (void)in_sizes; (void)n_in; (void)out_size;
  char* w = (char*)d_ws;
  size_t off = 0;
  auto alloc = [&](size_t bytes) -> void* {
    void* p = w + off;
    off = (off + bytes + 255) & ~(size_t)255;
    return p;
  };
  float* rope            = (float*)alloc(65536 * 4);
  unsigned short* wtqkv  = (unsigned short*)alloc((size_t)2304 * 768 * 2);
  unsigned short* wtao   = (unsigned short*)alloc((size_t)768 * 768 * 2);
  unsigned short* wtfc   = (unsigned short*)alloc((size_t)3072 * 768 * 2);
  unsigned short* wtgate = (unsigned short*)alloc((size_t)3072 * 768 * 2);
  unsigned short* wtproj = (unsigned short*)alloc((size_t)768 * 3072 * 2);
  float* zeroed          = (float*)alloc(14080 * 4);   // wcol2(9984) + orow2(2048) + mrow2(2048)
  unsigned short* h1     = (unsigned short*)alloc((size_t)2048 * 768 * 2);
  float* hrow1           = (float*)alloc(2048 * 4);
  unsigned short* qbuf   = (unsigned short*)alloc((size_t)2048 * 768 * 2);
  unsigned short* kbuf   = (unsigned short*)alloc((size_t)2048 * 768 * 2);
  unsigned short* vbuf   = (unsigned short*)alloc((size_t)2048 * 768 * 2);
  unsigned short* obuf   = (unsigned short*)alloc((size_t)2048 * 768 * 2);
  float* xo              = (float*)alloc((size_t)2048 * 768 * 4);
  unsigned short* h2     = (unsigned short*)alloc((size_t)2048 * 768 * 2);
  float* hrow2           = (float*)alloc(2048 * 4);
  unsigned short* mlp    = (unsigned short*)alloc((size_t)2048 * 3072 * 2);
  float* slabs           = (float*)alloc((size_t)4 * 2048 * 768 * 4);  // PROJ split-K partials
  if (off > ws_size) return;

  float* wcol2  = zeroed;
  float* orow2  = zeroed + 9984;
  float* mrow2  = zeroed + 9984 + 2048;
  float* c_qkv  = wcol2 + 0;
  float* c_ao   = wcol2 + 2304;
  float* c_fc   = wcol2 + 3072;
  float* c_gate = wcol2 + 6144;
  float* c_proj = wcol2 + 9216;

  const float* xin = (const float*)d_in[0];

  hipMemsetAsync(zeroed, 0, 14080 * 4, stream);
  k_rope<<<256, 256, 0, stream>>>(rope);

  k_transpose<<<dim3(72, 24), 256, 0, stream>>>((const float*)d_in[3],  wtqkv,  c_qkv,  2304, 768);
  k_transpose<<<dim3(24, 24), 256, 0, stream>>>((const float*)d_in[6],  wtao,   c_ao,   768,  768);
  k_transpose<<<dim3(96, 24), 256, 0, stream>>>((const float*)d_in[10], wtfc,   c_fc,   3072, 768);
  k_transpose<<<dim3(96, 24), 256, 0, stream>>>((const float*)d_in[13], wtgate, c_gate, 3072, 768);
  k_transpose<<<dim3(24, 96), 256, 0, stream>>>((const float*)d_in[16], wtproj, c_proj, 768,  3072);

  k_ln<<<2048, 256, 0, stream>>>(xin, (const float*)d_in[2], h1, hrow1);

  GemmArgs gq = {};
  gq.A = h1; gq.Bt = wtqkv; gq.arow2 = hrow1; gq.wcol2 = c_qkv;
  gq.bias = (const float*)d_in[4]; gq.alpha = (const float*)d_in[5];
  gq.N = 2304; gq.ks = 768;
  gq.rope = rope; gq.qo = qbuf; gq.ko = kbuf; gq.vo = vbuf;
  k_gemm<M_QKV, 24><<<dim3(32, 18), 256, 0, stream>>>(gq);

  k_attn<<<dim3(16, 24), 256, 0, stream>>>(qbuf, kbuf, vbuf, obuf, orow2);

  GemmArgs ga = {};
  ga.A = obuf; ga.Bt = wtao; ga.arow2 = orow2; ga.wcol2 = c_ao;
  ga.bias = (const float*)d_in[7]; ga.alpha = (const float*)d_in[8];
  ga.N = 768; ga.ks = 768;
  ga.xf = xin; ga.xo = xo;
  k_gemm<M_AO, 24><<<dim3(32, 6), 256, 0, stream>>>(ga);

  k_ln<<<2048, 256, 0, stream>>>(xo, (const float*)d_in[9], h2, hrow2);

  MlpArgs gm = {};
  gm.A = h2; gm.Bf = wtfc; gm.Bg = wtgate; gm.arow2 = hrow2;
  gm.w2f = c_fc; gm.w2g = c_gate;
  gm.bf = (const float*)d_in[11]; gm.bg = (const float*)d_in[14];
  gm.af_ = (const float*)d_in[12]; gm.ag_ = (const float*)d_in[15];
  gm.mlp = mlp; gm.mrow2 = mrow2;
  k_mlp<<<dim3(32, 24), 256, 0, stream>>>(gm);

  GemmArgs gp = {};
  gp.A = mlp; gp.Bt = wtproj;
  gp.N = 768; gp.ks = 3072;
  gp.part = slabs;
  k_gemm<M_PART, 24><<<dim3(32, 6, 4), 256, 0, stream>>>(gp);

  EpiArgs ge = {};
  ge.slab = slabs; ge.arow2 = mrow2; ge.wcol2 = c_proj;
  ge.bias = (const float*)d_in[17]; ge.alpha = (const float*)d_in[18];
  ge.xo = xo; ge.outf = (float*)d_out;
  k_proj_epi<<<1536, 256, 0, stream>>>(ge);
}

// Round 5
// 290.782 us; speedup vs baseline: 1.4186x; 1.0710x over previous
//
#include <hip/hip_runtime.h>
#include <cstdint>

#define DEVFN static __device__ __forceinline__

typedef __bf16 bf16x8 __attribute__((ext_vector_type(8)));
typedef float f32x4 __attribute__((ext_vector_type(4)));
typedef unsigned short us4 __attribute__((ext_vector_type(4)));

DEVFN unsigned short f2bf(float f) {
  unsigned u = __float_as_uint(f);
  u += 0x7fffu + ((u >> 16) & 1u);           // round-to-nearest-even
  return (unsigned short)(u >> 16);
}
DEVFN float bf2f(unsigned short h) { return __uint_as_float(((unsigned)h) << 16); }
DEVFN void async16(const void* g, void* l) {
  __builtin_amdgcn_global_load_lds((__attribute__((address_space(1))) const void*)g,
                                   (__attribute__((address_space(3))) void*)l, 16, 0, 0);
}
DEVFN float gelu_t(float u) {
  return 0.5f * u * (1.f + tanhf(0.7978845608028654f * (u + 0.044715f * u * u * u)));
}
// XCD swizzle: lin%8 = XCD class; give each XCD a contiguous slice of g-space
DEVFN int xcd_swizzle(int lin, int total) {
  return (lin & 7) * (total >> 3) + (lin >> 3);
}

// ---------------- rope table ------------------------------------------------
__global__ __launch_bounds__(256) void k_rope(float* __restrict__ rope) {
  int g = blockIdx.x * 256 + threadIdx.x;
  int t = g >> 6, dd = g & 63, i = dd & 31;
  float fr = __expf(-0.2878231366242558f * (float)i);   // ln(1e4)/32
  float ang = (float)t * fr;
  rope[g] = (dd < 32) ? cosf(ang) : sinf(ang);
}

// ---------------- merged weight transpose (KxN f32 -> NxK bf16) + col norms -
struct TrArgs {
  const float* W[5]; unsigned short* Wt[5]; float* cn[5];
  int N[5]; int off[6];
};
__global__ __launch_bounds__(256) void k_transpose(TrArgs a) {
  __shared__ float tile[32][33];
  __shared__ float part[8][32];
  int lin = blockIdx.x;
  int e = 0;
  while (lin >= a.off[e + 1]) ++e;
  int local = lin - a.off[e];
  const int N = a.N[e];
  int nbx = N >> 5;
  int tn = local % nbx, tk = local / nbx;
  const float* W = a.W[e];
  unsigned short* Wt = a.Wt[e];
  float* cn = a.cn[e];
  const int K = (e == 4) ? 3072 : 768;
  int tx = threadIdx.x & 31, ty = threadIdx.x >> 5;
  float acc = 0.f;
  #pragma unroll
  for (int j = 0; j < 4; ++j) {
    int r = ty + j * 8;
    float v = W[(long)(tk * 32 + r) * N + tn * 32 + tx];
    tile[r][tx] = v;
    acc += v * v;
  }
  part[ty][tx] = acc;
  __syncthreads();
  #pragma unroll
  for (int j = 0; j < 4; ++j) {
    int rr = ty + j * 8;
    Wt[(long)(tn * 32 + rr) * K + tk * 32 + tx] = f2bf(tile[tx][rr]);
  }
  if (ty == 0) {
    float s = part[0][tx];
    #pragma unroll
    for (int jj = 1; jj < 8; ++jj) s += part[jj][tx];
    atomicAdd(&cn[tn * 32 + tx], s);
  }
}

// ---------------- layernorm (f32 in) -> bf16 h + row sum(h^2) ---------------
__global__ __launch_bounds__(256) void k_ln(const float* __restrict__ x,
    const float* __restrict__ g, unsigned short* __restrict__ h, float* __restrict__ row2) {
  int row = blockIdx.x, tid = threadIdx.x;
  const float* xr = x + (long)row * 768;
  float v0 = xr[tid], v1 = xr[tid + 256], v2 = xr[tid + 512];
  float s = v0 + v1 + v2;
  float ss = v0 * v0 + v1 * v1 + v2 * v2;
  #pragma unroll
  for (int o = 32; o; o >>= 1) { s += __shfl_xor(s, o); ss += __shfl_xor(ss, o); }
  __shared__ float red[12];
  int wv = tid >> 6;
  if ((tid & 63) == 0) { red[wv] = s; red[wv + 4] = ss; }
  __syncthreads();
  s = red[0] + red[1] + red[2] + red[3];
  ss = red[4] + red[5] + red[6] + red[7];
  float mu = s * (1.f / 768.f);
  float var = ss * (1.f / 768.f) - mu * mu;
  float rs = rsqrtf(var + 1e-6f);
  float h0 = (v0 - mu) * rs * g[tid];
  float h1 = (v1 - mu) * rs * g[tid + 256];
  float h2 = (v2 - mu) * rs * g[tid + 512];
  unsigned short* hr = h + (long)row * 768;
  hr[tid] = f2bf(h0); hr[tid + 256] = f2bf(h1); hr[tid + 512] = f2bf(h2);
  float p = h0 * h0 + h1 * h1 + h2 * h2;
  #pragma unroll
  for (int o = 32; o; o >>= 1) p += __shfl_xor(p, o);
  if ((tid & 63) == 0) red[8 + wv] = p;
  __syncthreads();
  if (tid == 0) row2[row] = red[8] + red[9] + red[10] + red[11];
}

// ---------------- yat GEMM: 64x128 tile, 3-buffer distance-2, XCD swizzle ---
constexpr int M_QKV = 0, M_AO = 1, M_PART = 2;

struct GemmArgs {
  const unsigned short* A; const unsigned short* Bt;
  const float* arow2; const float* wcol2; const float* bias; const float* alpha;
  int N; int ks;                                        // ks = row stride in K dim
  const float* rope;                                    // QKV
  unsigned short* qo; unsigned short* ko; unsigned short* vo;  // QKV
  const float* xf; float* xo;                           // AO: residual in/out (f32)
  float* part;                                          // PART: f32 slab base
};

template <int MODE, int NI, int NBM, int NBN, int NZ>
__global__ __launch_bounds__(256, 4) void k_gemm(GemmArgs p) {
  __shared__ __align__(16) unsigned short As[3][2048];   // 64 x 32
  __shared__ __align__(16) unsigned short Bs[3][4096];   // 128 x 32
  const int tid = threadIdx.x, wave = tid >> 6, lane = tid & 63;
  const int quad = lane >> 4, l = lane & 15;
  constexpr int TOTAL = NBM * NBN * NZ;
  const int g = xcd_swizzle(blockIdx.x, TOTAL);
  const int bm = (g % NBM) * 64;
  const int rest = g / NBM;
  const int bn = (rest % NBN) * 128;
  const int z = rest / NBN;
  const int kb = z * (NI * 32);
  const int ks = p.ks;
  const int wm = (wave & 1) * 32, wn = (wave >> 1) * 64;
  const f32x4 fzero = {0.f, 0.f, 0.f, 0.f};
  f32x4 acc[2][4];
  #pragma unroll
  for (int i = 0; i < 2; ++i)
    #pragma unroll
    for (int j = 0; j < 4; ++j) acc[i][j] = fzero;
  const int sw = (l >> 1) & 3;

  auto stage = [&](int s, int k0) {
    {
      int ci = tid;
      int r = ci >> 2;
      int c = (ci & 3) ^ ((r >> 1) & 3);
      async16(p.A + (long)(bm + r) * ks + kb + k0 + c * 8, &As[s][ci * 8]);
    }
    #pragma unroll
    for (int it = 0; it < 2; ++it) {
      int ci = tid + it * 256;
      int r = ci >> 2;
      int c = (ci & 3) ^ ((r >> 1) & 3);
      async16(p.Bt + (long)(bn + r) * ks + kb + k0 + c * 8, &Bs[s][ci * 8]);
    }
  };
  auto compute = [&](int s) {
    bf16x8 af[2], bfv[4];
    #pragma unroll
    for (int mi = 0; mi < 2; ++mi)
      af[mi] = *(const bf16x8*)&As[s][(wm + mi * 16 + l) * 32 + ((quad ^ sw) * 8)];
    #pragma unroll
    for (int ni = 0; ni < 4; ++ni)
      bfv[ni] = *(const bf16x8*)&Bs[s][(wn + ni * 16 + l) * 32 + ((quad ^ sw) * 8)];
    #pragma unroll
    for (int mi = 0; mi < 2; ++mi)
      #pragma unroll
      for (int ni = 0; ni < 4; ++ni)
        acc[mi][ni] = __builtin_amdgcn_mfma_f32_16x16x32_bf16(af[mi], bfv[ni], acc[mi][ni], 0, 0, 0);
  };
  auto iter = [&](int s, int i) {
    if (i + 1 >= NI) { asm volatile("s_waitcnt vmcnt(0)" ::: "memory"); }
    else             { asm volatile("s_waitcnt vmcnt(3)" ::: "memory"); }
    __builtin_amdgcn_s_barrier();
    asm volatile("" ::: "memory");
    if (i + 2 < NI) stage(s == 0 ? 2 : s - 1, (i + 2) * 32);
    compute(s);
  };

  stage(0, 0);
  stage(1, 32);
  int i = 0;
  while (i < NI) {          // NI % 3 == 0
    iter(0, i); ++i;
    iter(1, i); ++i;
    iter(2, i); ++i;
  }

  if constexpr (MODE == M_PART) {
    float* slab = p.part + (long)z * (2048 * 768);
    #pragma unroll
    for (int ni = 0; ni < 4; ++ni) {
      const int j = bn + wn + ni * 16 + l;
      #pragma unroll
      for (int mi = 0; mi < 2; ++mi) {
        const int i0 = bm + wm + mi * 16 + quad * 4;
        #pragma unroll
        for (int rg = 0; rg < 4; ++rg)
          slab[(long)(i0 + rg) * 768 + j] = acc[mi][ni][rg];
      }
    }
  } else {
    const float al = p.alpha[0];
    const float nn = (float)p.N;
    const float ys = powf(sqrtf(nn) / log1pf(nn), al);
    #pragma unroll
    for (int ni = 0; ni < 4; ++ni) {
      const int j = bn + wn + ni * 16 + l;
      const float w2 = p.wcol2[j];
      const float bj = p.bias[j];
      int s3 = 0, hh = 0, dd = 0;
      if constexpr (MODE == M_QKV) { s3 = j / 768; int rem = j - s3 * 768; hh = rem >> 6; dd = rem & 63; }
      #pragma unroll
      for (int mi = 0; mi < 2; ++mi) {
        const int i0 = bm + wm + mi * 16 + quad * 4;
        float vv[4];
        #pragma unroll
        for (int rg = 0; rg < 4; ++rg) {
          const float y = acc[mi][ni][rg];
          const float dist = p.arow2[i0 + rg] + w2 - 2.f * y + 1e-6f;
          vv[rg] = (y * y / dist + bj) * ys;
        }
        if constexpr (MODE == M_QKV) {
          int b = i0 >> 10, t0 = i0 & 1023;
          if (s3 == 2) {
            us4 pk = {f2bf(vv[0]), f2bf(vv[1]), f2bf(vv[2]), f2bf(vv[3])};
            *(us4*)&p.vo[((long)(b * 12 + hh) * 64 + dd) * 1024 + t0] = pk;    // V^T (B,H,D,T)
          } else {
            unsigned short* dst = (s3 == 0) ? p.qo : p.ko;                     // (B,H,T,D)
            #pragma unroll
            for (int rg = 0; rg < 4; ++rg) {
              float ro = p.rope[(t0 + rg) * 64 + dd];
              dst[((long)(b * 12 + hh) * 1024 + t0 + rg) * 64 + dd] = f2bf(vv[rg] * ro);
            }
          }
        } else {  // M_AO
          #pragma unroll
          for (int rg = 0; rg < 4; ++rg) {
            long idx = (long)(i0 + rg) * 768 + j;
            p.xo[idx] = p.xf[idx] + vv[rg];
          }
        }
      }
    }
  }
}

// ---------------- PROJ reduce (2 slabs) + yat epilogue + residual -----------
struct EpiArgs {
  const float* slab; const float* arow2; const float* wcol2;
  const float* bias; const float* alpha; const float* xo; float* outf;
};
__global__ __launch_bounds__(256) void k_proj_epi(EpiArgs p) {
  int g = blockIdx.x * 256 + threadIdx.x;   // 393216 = 2048*768/4
  int i = g / 192, jv = (g - i * 192) * 4;
  long base = (long)i * 768 + jv;
  f32x4 y = *(const f32x4*)(p.slab + base);
  y += *(const f32x4*)(p.slab + 1572864 + base);
  const float a2 = p.arow2[i];
  const float ys = powf(sqrtf(768.f) / log1pf(768.f), p.alpha[0]);
  f32x4 xo4 = *(const f32x4*)(p.xo + base);
  f32x4 out;
  #pragma unroll
  for (int c = 0; c < 4; ++c) {
    float yy = y[c];
    float dist = a2 + p.wcol2[jv + c] - 2.f * yy + 1e-6f;
    out[c] = xo4[c] + (yy * yy / dist + p.bias[jv + c]) * ys;
  }
  *(f32x4*)(p.outf + base) = out;
}

// ---------------- merged FC+GATE yat GEMM (128x128, 2-buffer, swizzled) -----
struct MlpArgs {
  const unsigned short* A; const unsigned short* Bf; const unsigned short* Bg;
  const float* arow2; const float* w2f; const float* w2g;
  const float* bf; const float* bg; const float* af_; const float* ag_;
  unsigned short* mlp; float* mrow2;
};

__global__ __launch_bounds__(256, 2) void k_mlp(MlpArgs p) {
  constexpr int NI = 24, K = 768;
  __shared__ __align__(16) unsigned short As[2][4096];
  __shared__ __align__(16) unsigned short Bfs[2][4096];
  __shared__ __align__(16) unsigned short Bgs[2][4096];
  const int tid = threadIdx.x, wave = tid >> 6, lane = tid & 63;
  const int quad = lane >> 4, l = lane & 15;
  const int g = xcd_swizzle(blockIdx.x, 16 * 24);
  const int bm = (g % 16) * 128, bn = (g / 16) * 128;
  const int wm = (wave & 1) * 64, wn = (wave >> 1) * 64;
  const f32x4 fzero = {0.f, 0.f, 0.f, 0.f};
  f32x4 accf[4][4], accg[4][4];
  #pragma unroll
  for (int i = 0; i < 4; ++i)
    #pragma unroll
    for (int j = 0; j < 4; ++j) { accf[i][j] = fzero; accg[i][j] = fzero; }
  const int sw = (l >> 1) & 3;

  auto stage = [&](int s, int k0) {
    #pragma unroll
    for (int it = 0; it < 2; ++it) {
      int ci = tid + it * 256;
      int r = ci >> 2;
      int c = (ci & 3) ^ ((r >> 1) & 3);
      async16(p.A  + (long)(bm + r) * K + k0 + c * 8, &As[s][ci * 8]);
      async16(p.Bf + (long)(bn + r) * K + k0 + c * 8, &Bfs[s][ci * 8]);
      async16(p.Bg + (long)(bn + r) * K + k0 + c * 8, &Bgs[s][ci * 8]);
    }
  };

  stage(0, 0);
  for (int i = 0; i < NI; ++i) {
    int s = i & 1;
    asm volatile("s_waitcnt vmcnt(0)" ::: "memory");
    __builtin_amdgcn_s_barrier();
    asm volatile("" ::: "memory");
    if (i + 1 < NI) stage(s ^ 1, (i + 1) * 32);
    bf16x8 af[4], bff[4], bfg[4];
    #pragma unroll
    for (int mi = 0; mi < 4; ++mi)
      af[mi] = *(const bf16x8*)&As[s][(wm + mi * 16 + l) * 32 + ((quad ^ sw) * 8)];
    #pragma unroll
    for (int ni = 0; ni < 4; ++ni) {
      bff[ni] = *(const bf16x8*)&Bfs[s][(wn + ni * 16 + l) * 32 + ((quad ^ sw) * 8)];
      bfg[ni] = *(const bf16x8*)&Bgs[s][(wn + ni * 16 + l) * 32 + ((quad ^ sw) * 8)];
    }
    #pragma unroll
    for (int mi = 0; mi < 4; ++mi)
      #pragma unroll
      for (int ni = 0; ni < 4; ++ni) {
        accf[mi][ni] = __builtin_amdgcn_mfma_f32_16x16x32_bf16(af[mi], bff[ni], accf[mi][ni], 0, 0, 0);
        accg[mi][ni] = __builtin_amdgcn_mfma_f32_16x16x32_bf16(af[mi], bfg[ni], accg[mi][ni], 0, 0, 0);
      }
  }

  const float ysf = powf(sqrtf(3072.f) / log1pf(3072.f), p.af_[0]);
  const float ysg = powf(sqrtf(3072.f) / log1pf(3072.f), p.ag_[0]);
  float w2f[4], w2g[4], bjf[4], bjg[4]; int js[4];
  #pragma unroll
  for (int ni = 0; ni < 4; ++ni) {
    int j = bn + wn + ni * 16 + l;
    js[ni] = j; w2f[ni] = p.w2f[j]; w2g[ni] = p.w2g[j]; bjf[ni] = p.bf[j]; bjg[ni] = p.bg[j];
  }
  #pragma unroll
  for (int mi = 0; mi < 4; ++mi) {
    #pragma unroll
    for (int rg = 0; rg < 4; ++rg) {
      const int ii = bm + wm + mi * 16 + quad * 4 + rg;
      const float a2 = p.arow2[ii];
      float rsum = 0.f;
      #pragma unroll
      for (int ni = 0; ni < 4; ++ni) {
        float yf = accf[mi][ni][rg];
        float gate = (yf * yf / (a2 + w2f[ni] - 2.f * yf + 1e-6f) + bjf[ni]) * ysf;
        float yg = accg[mi][ni][rg];
        float u  = (yg * yg / (a2 + w2g[ni] - 2.f * yg + 1e-6f) + bjg[ni]) * ysg;
        float out = gelu_t(u) * gate;
        p.mlp[(long)ii * 3072 + js[ni]] = f2bf(out);
        rsum += out * out;
      }
      #pragma unroll
      for (int o = 8; o; o >>= 1) rsum += __shfl_xor(rsum, o);
      if (l == 0) atomicAdd(&p.mrow2[ii], rsum);
    }
  }
}

// ---------------- flash attention: 64-row Q tiles, causal, swizzled ---------
__global__ __launch_bounds__(256) void k_attn(const unsigned short* __restrict__ qb,
    const unsigned short* __restrict__ kb, const unsigned short* __restrict__ vb,
    unsigned short* __restrict__ ob, float* __restrict__ orow2) {
  __shared__ __align__(16) unsigned short Qs[64 * 64];
  __shared__ __align__(16) unsigned short Ks[64 * 64];
  __shared__ __align__(16) unsigned short Vs[64 * 64];
  __shared__ __align__(16) unsigned short Ps[4 * 16 * 64];
  const int tid = threadIdx.x, wave = tid >> 6, lane = tid & 63;
  const int quad = lane >> 4, l = lane & 15;
  const int g = xcd_swizzle(blockIdx.x, 16 * 24);
  const int qt = g % 16, bh = g / 16;
  const int b = bh / 12, hh = bh % 12;
  const int q0 = qt * 64;
  const f32x4 fzero = {0.f, 0.f, 0.f, 0.f};

  const unsigned short* qg = qb + ((long)bh * 1024 + q0) * 64;
  #pragma unroll
  for (int it = 0; it < 2; ++it) {
    int ci = tid + it * 256;
    int r = ci >> 3;
    int c = (ci & 7) ^ (r & 7);
    async16(qg + (long)r * 64 + c * 8, &Qs[ci * 8]);
  }
  __builtin_amdgcn_s_waitcnt(0);
  __syncthreads();
  bf16x8 aq[2];
  #pragma unroll
  for (int ks = 0; ks < 2; ++ks)
    aq[ks] = *(const bf16x8*)&Qs[(wave * 16 + l) * 64 + (((ks * 4 + quad) ^ (l & 7)) * 8)];

  f32x4 O[4];
  float mi_[4], li[4];
  #pragma unroll
  for (int f = 0; f < 4; ++f) O[f] = fzero;
  #pragma unroll
  for (int r = 0; r < 4; ++r) { mi_[r] = -1e30f; li[r] = 0.f; }

  for (int jt = 0; jt <= qt; ++jt) {
    __syncthreads();
    const unsigned short* kg = kb + ((long)bh * 1024 + jt * 64) * 64;
    const unsigned short* vg = vb + (long)bh * 64 * 1024 + jt * 64;
    #pragma unroll
    for (int it = 0; it < 2; ++it) {
      int ci = tid + it * 256;
      int r = ci >> 3;
      int c = (ci & 7) ^ (r & 7);
      async16(kg + (long)r * 64 + c * 8, &Ks[ci * 8]);
      async16(vg + (long)r * 1024 + c * 8, &Vs[ci * 8]);
    }
    __builtin_amdgcn_s_waitcnt(0);
    __syncthreads();

    f32x4 S[4];
    #pragma unroll
    for (int f = 0; f < 4; ++f) S[f] = fzero;
    #pragma unroll
    for (int ks = 0; ks < 2; ++ks) {
      #pragma unroll
      for (int f = 0; f < 4; ++f) {
        bf16x8 bk = *(const bf16x8*)&Ks[(f * 16 + l) * 64 + (((ks * 4 + quad) ^ (l & 7)) * 8)];
        S[f] = __builtin_amdgcn_mfma_f32_16x16x32_bf16(aq[ks], bk, S[f], 0, 0, 0);
      }
    }
    const bool diag = (jt == qt);
    #pragma unroll
    for (int f = 0; f < 4; ++f)
      #pragma unroll
      for (int r = 0; r < 4; ++r) {
        float v = S[f][r] * 0.125f;
        if (diag && (f * 16 + l > wave * 16 + quad * 4 + r)) v = -1e30f;
        S[f][r] = v;
      }
    #pragma unroll
    for (int r = 0; r < 4; ++r) {
      float mx = fmaxf(fmaxf(S[0][r], S[1][r]), fmaxf(S[2][r], S[3][r]));
      #pragma unroll
      for (int o = 8; o; o >>= 1) mx = fmaxf(mx, __shfl_xor(mx, o));
      float mnew = fmaxf(mi_[r], mx);
      float alr = __expf(mi_[r] - mnew);
      float sum = 0.f;
      #pragma unroll
      for (int f = 0; f < 4; ++f) {
        float e = __expf(S[f][r] - mnew);
        S[f][r] = e;
        sum += e;
      }
      #pragma unroll
      for (int o = 8; o; o >>= 1) sum += __shfl_xor(sum, o);
      li[r] = li[r] * alr + sum;
      #pragma unroll
      for (int f = 0; f < 4; ++f) O[f][r] *= alr;
      mi_[r] = mnew;
    }
    #pragma unroll
    for (int f = 0; f < 4; ++f)
      #pragma unroll
      for (int r = 0; r < 4; ++r) {
        int i = quad * 4 + r;
        int j = f * 16 + l;
        int pch = (j >> 3) ^ (i & 7);
        Ps[wave * 1024 + i * 64 + pch * 8 + (j & 7)] = f2bf(S[f][r]);
      }
    #pragma unroll
    for (int ks = 0; ks < 2; ++ks) {
      bf16x8 ap = *(const bf16x8*)&Ps[wave * 1024 + l * 64 + (((ks * 4 + quad) ^ (l & 7)) * 8)];
      #pragma unroll
      for (int f = 0; f < 4; ++f) {
        bf16x8 bv = *(const bf16x8*)&Vs[(f * 16 + l) * 64 + (((ks * 4 + quad) ^ (l & 7)) * 8)];
        O[f] = __builtin_amdgcn_mfma_f32_16x16x32_bf16(ap, bv, O[f], 0, 0, 0);
      }
    }
  }
  #pragma unroll
  for (int f = 0; f < 4; ++f)
    #pragma unroll
    for (int r = 0; r < 4; ++r) {
      int t = q0 + wave * 16 + quad * 4 + r;
      int dd = f * 16 + l;
      float v = O[f][r] / li[r];
      ob[((long)(b * 1024 + t) * 12 + hh) * 64 + dd] = f2bf(v);  // (B,T,H,D)
    }
  #pragma unroll
  for (int r = 0; r < 4; ++r) {
    float rsum = 0.f;
    #pragma unroll
    for (int f = 0; f < 4; ++f) { float v = O[f][r] / li[r]; rsum += v * v; }
    #pragma unroll
    for (int o = 8; o; o >>= 1) rsum += __shfl_xor(rsum, o);
    if (l == 0) {
      int t = q0 + wave * 16 + quad * 4 + r;
      atomicAdd(&orow2[b * 1024 + t], rsum);
    }
  }
}

// ---------------- host ------------------------------------------------------
extern "C" void kernel_launch(void* const* d_in, const int* in_sizes, int n_in,
                              void* d_out, int out_size, void* d_ws, size_t ws_size,
                              hipStream_t stream) {
  (void)in_sizes; (void)n_in; (void)out_size;
  char* w = (char*)d_ws;
  size_t off = 0;
  auto alloc = [&](size_t bytes) -> void* {
    void* p = w + off;
    off = (off + bytes + 255) & ~(size_t)255;
    return p;
  };
  float* rope            = (float*)alloc(65536 * 4);
  unsigned short* wtqkv  = (unsigned short*)alloc((size_t)2304 * 768 * 2);
  unsigned short* wtao   = (unsigned short*)alloc((size_t)768 * 768 * 2);
  unsigned short* wtfc   = (unsigned short*)alloc((size_t)3072 * 768 * 2);
  unsigned short* wtgate = (unsigned short*)alloc((size_t)3072 * 768 * 2);
  unsigned short* wtproj = (unsigned short*)alloc((size_t)768 * 3072 * 2);
  float* zeroed          = (float*)alloc(14080 * 4);   // wcol2(9984) + orow2(2048) + mrow2(2048)
  unsigned short* h1     = (unsigned short*)alloc((size_t)2048 * 768 * 2);
  float* hrow1           = (float*)alloc(2048 * 4);
  unsigned short* qbuf   = (unsigned short*)alloc((size_t)2048 * 768 * 2);
  unsigned short* kbuf   = (unsigned short*)alloc((size_t)2048 * 768 * 2);
  unsigned short* vbuf   = (unsigned short*)alloc((size_t)2048 * 768 * 2);
  unsigned short* obuf   = (unsigned short*)alloc((size_t)2048 * 768 * 2);
  float* xo              = (float*)alloc((size_t)2048 * 768 * 4);
  unsigned short* h2     = (unsigned short*)alloc((size_t)2048 * 768 * 2);
  float* hrow2           = (float*)alloc(2048 * 4);
  unsigned short* mlp    = (unsigned short*)alloc((size_t)2048 * 3072 * 2);
  float* slabs           = (float*)alloc((size_t)2 * 2048 * 768 * 4);  // PROJ split-K partials
  if (off > ws_size) return;

  float* wcol2  = zeroed;
  float* orow2  = zeroed + 9984;
  float* mrow2  = zeroed + 9984 + 2048;
  float* c_qkv  = wcol2 + 0;
  float* c_ao   = wcol2 + 2304;
  float* c_fc   = wcol2 + 3072;
  float* c_gate = wcol2 + 6144;
  float* c_proj = wcol2 + 9216;

  const float* xin = (const float*)d_in[0];

  hipMemsetAsync(zeroed, 0, 14080 * 4, stream);
  k_rope<<<256, 256, 0, stream>>>(rope);

  // merged transpose: qkv(1728) ao(576) fc(2304) gate(2304) proj(2304) = 9216
  TrArgs ta;
  ta.W[0] = (const float*)d_in[3];  ta.Wt[0] = wtqkv;  ta.cn[0] = c_qkv;  ta.N[0] = 2304;
  ta.W[1] = (const float*)d_in[6];  ta.Wt[1] = wtao;   ta.cn[1] = c_ao;   ta.N[1] = 768;
  ta.W[2] = (const float*)d_in[10]; ta.Wt[2] = wtfc;   ta.cn[2] = c_fc;   ta.N[2] = 3072;
  ta.W[3] = (const float*)d_in[13]; ta.Wt[3] = wtgate; ta.cn[3] = c_gate; ta.N[3] = 3072;
  ta.W[4] = (const float*)d_in[16]; ta.Wt[4] = wtproj; ta.cn[4] = c_proj; ta.N[4] = 768;
  ta.off[0] = 0; ta.off[1] = 1728; ta.off[2] = 2304; ta.off[3] = 4608;
  ta.off[4] = 6912; ta.off[5] = 9216;
  k_transpose<<<9216, 256, 0, stream>>>(ta);

  k_ln<<<2048, 256, 0, stream>>>(xin, (const float*)d_in[2], h1, hrow1);

  GemmArgs gq = {};
  gq.A = h1; gq.Bt = wtqkv; gq.arow2 = hrow1; gq.wcol2 = c_qkv;
  gq.bias = (const float*)d_in[4]; gq.alpha = (const float*)d_in[5];
  gq.N = 2304; gq.ks = 768;
  gq.rope = rope; gq.qo = qbuf; gq.ko = kbuf; gq.vo = vbuf;
  k_gemm<M_QKV, 24, 32, 18, 1><<<576, 256, 0, stream>>>(gq);

  k_attn<<<384, 256, 0, stream>>>(qbuf, kbuf, vbuf, obuf, orow2);

  GemmArgs ga = {};
  ga.A = obuf; ga.Bt = wtao; ga.arow2 = orow2; ga.wcol2 = c_ao;
  ga.bias = (const float*)d_in[7]; ga.alpha = (const float*)d_in[8];
  ga.N = 768; ga.ks = 768;
  ga.xf = xin; ga.xo = xo;
  k_gemm<M_AO, 24, 32, 6, 1><<<192, 256, 0, stream>>>(ga);

  k_ln<<<2048, 256, 0, stream>>>(xo, (const float*)d_in[9], h2, hrow2);

  MlpArgs gm = {};
  gm.A = h2; gm.Bf = wtfc; gm.Bg = wtgate; gm.arow2 = hrow2;
  gm.w2f = c_fc; gm.w2g = c_gate;
  gm.bf = (const float*)d_in[11]; gm.bg = (const float*)d_in[14];
  gm.af_ = (const float*)d_in[12]; gm.ag_ = (const float*)d_in[15];
  gm.mlp = mlp; gm.mrow2 = mrow2;
  k_mlp<<<384, 256, 0, stream>>>(gm);

  GemmArgs gp = {};
  gp.A = mlp; gp.Bt = wtproj;
  gp.N = 768; gp.ks = 3072;
  gp.part = slabs;
  k_gemm<M_PART, 48, 32, 6, 2><<<384, 256, 0, stream>>>(gp);

  EpiArgs ge = {};
  ge.slab = slabs; ge.arow2 = mrow2; ge.wcol2 = c_proj;
  ge.bias = (const float*)d_in[17]; ge.alpha = (const float*)d_in[18];
  ge.xo = xo; ge.outf = (float*)d_out;
  k_proj_epi<<<1536, 256, 0, stream>>>(ge);
}

// Round 6
// 281.093 us; speedup vs baseline: 1.4675x; 1.0345x over previous
//
#include <hip/hip_runtime.h>
#include <cstdint>

#define DEVFN static __device__ __forceinline__

typedef __bf16 bf16x8 __attribute__((ext_vector_type(8)));
typedef float f32x4 __attribute__((ext_vector_type(4)));
typedef unsigned short us4 __attribute__((ext_vector_type(4)));

DEVFN unsigned short f2bf(float f) {
  unsigned u = __float_as_uint(f);
  u += 0x7fffu + ((u >> 16) & 1u);           // round-to-nearest-even
  return (unsigned short)(u >> 16);
}
DEVFN float bf2f(unsigned short h) { return __uint_as_float(((unsigned)h) << 16); }
DEVFN void async16(const void* g, void* l) {
  __builtin_amdgcn_global_load_lds((__attribute__((address_space(1))) const void*)g,
                                   (__attribute__((address_space(3))) void*)l, 16, 0, 0);
}
DEVFN float gelu_t(float u) {
  return 0.5f * u * (1.f + tanhf(0.7978845608028654f * (u + 0.044715f * u * u * u)));
}
// XCD swizzle: lin%8 = XCD class; give each XCD a contiguous slice of g-space
DEVFN int xcd_swizzle(int lin, int total) {
  return (lin & 7) * (total >> 3) + (lin >> 3);
}

// ---------------- merged prep: rope + 5 transposes + LN1 --------------------
struct PrepArgs {
  float* rope;
  const float* W[5]; unsigned short* Wt[5]; float* cn[5];
  int N[5]; int off[6];
  const float* x; const float* g1s; unsigned short* h1; float* hrow1;
};
__global__ __launch_bounds__(256) void k_prep(PrepArgs a) {
  __shared__ float tile[32][33];
  __shared__ float part[8][32];
  __shared__ float red[12];
  const int bid = blockIdx.x, tid = threadIdx.x;
  if (bid < 256) {                       // rope table
    int g = bid * 256 + tid;
    int t = g >> 6, dd = g & 63, i = dd & 31;
    float fr = __expf(-0.2878231366242558f * (float)i);   // ln(1e4)/32
    float ang = (float)t * fr;
    a.rope[g] = (dd < 32) ? cosf(ang) : sinf(ang);
  } else if (bid < 9472) {               // weight transpose + col sq-norms
    int lin = bid - 256;
    int e = 0;
    while (lin >= a.off[e + 1]) ++e;
    int local = lin - a.off[e];
    const int N = a.N[e];
    int nbx = N >> 5;
    int tn = local % nbx, tk = local / nbx;
    const float* W = a.W[e];
    unsigned short* Wt = a.Wt[e];
    float* cn = a.cn[e];
    const int K = (e == 4) ? 3072 : 768;
    int tx = tid & 31, ty = tid >> 5;
    float acc = 0.f;
    #pragma unroll
    for (int j = 0; j < 4; ++j) {
      int r = ty + j * 8;
      float v = W[(long)(tk * 32 + r) * N + tn * 32 + tx];
      tile[r][tx] = v;
      acc += v * v;
    }
    part[ty][tx] = acc;
    __syncthreads();
    #pragma unroll
    for (int j = 0; j < 4; ++j) {
      int rr = ty + j * 8;
      Wt[(long)(tn * 32 + rr) * K + tk * 32 + tx] = f2bf(tile[tx][rr]);
    }
    if (ty == 0) {
      float s = part[0][tx];
      #pragma unroll
      for (int jj = 1; jj < 8; ++jj) s += part[jj][tx];
      atomicAdd(&cn[tn * 32 + tx], s);
    }
  } else {                               // LN1
    int row = bid - 9472;
    const float* xr = a.x + (long)row * 768;
    float v0 = xr[tid], v1 = xr[tid + 256], v2 = xr[tid + 512];
    float s = v0 + v1 + v2;
    float ss = v0 * v0 + v1 * v1 + v2 * v2;
    #pragma unroll
    for (int o = 32; o; o >>= 1) { s += __shfl_xor(s, o); ss += __shfl_xor(ss, o); }
    int wv = tid >> 6;
    if ((tid & 63) == 0) { red[wv] = s; red[wv + 4] = ss; }
    __syncthreads();
    s = red[0] + red[1] + red[2] + red[3];
    ss = red[4] + red[5] + red[6] + red[7];
    float mu = s * (1.f / 768.f);
    float var = ss * (1.f / 768.f) - mu * mu;
    float rs = rsqrtf(var + 1e-6f);
    float h0 = (v0 - mu) * rs * a.g1s[tid];
    float h1 = (v1 - mu) * rs * a.g1s[tid + 256];
    float h2 = (v2 - mu) * rs * a.g1s[tid + 512];
    unsigned short* hr = a.h1 + (long)row * 768;
    hr[tid] = f2bf(h0); hr[tid + 256] = f2bf(h1); hr[tid + 512] = f2bf(h2);
    float p = h0 * h0 + h1 * h1 + h2 * h2;
    #pragma unroll
    for (int o = 32; o; o >>= 1) p += __shfl_xor(p, o);
    if ((tid & 63) == 0) red[8 + wv] = p;
    __syncthreads();
    if (tid == 0) a.hrow1[row] = red[8] + red[9] + red[10] + red[11];
  }
}

// ---------------- layernorm (f32 in) -> bf16 h + row sum(h^2) ---------------
__global__ __launch_bounds__(256) void k_ln(const float* __restrict__ x,
    const float* __restrict__ g, unsigned short* __restrict__ h, float* __restrict__ row2) {
  int row = blockIdx.x, tid = threadIdx.x;
  const float* xr = x + (long)row * 768;
  float v0 = xr[tid], v1 = xr[tid + 256], v2 = xr[tid + 512];
  float s = v0 + v1 + v2;
  float ss = v0 * v0 + v1 * v1 + v2 * v2;
  #pragma unroll
  for (int o = 32; o; o >>= 1) { s += __shfl_xor(s, o); ss += __shfl_xor(ss, o); }
  __shared__ float red[12];
  int wv = tid >> 6;
  if ((tid & 63) == 0) { red[wv] = s; red[wv + 4] = ss; }
  __syncthreads();
  s = red[0] + red[1] + red[2] + red[3];
  ss = red[4] + red[5] + red[6] + red[7];
  float mu = s * (1.f / 768.f);
  float var = ss * (1.f / 768.f) - mu * mu;
  float rs = rsqrtf(var + 1e-6f);
  float h0 = (v0 - mu) * rs * g[tid];
  float h1 = (v1 - mu) * rs * g[tid + 256];
  float h2 = (v2 - mu) * rs * g[tid + 512];
  unsigned short* hr = h + (long)row * 768;
  hr[tid] = f2bf(h0); hr[tid + 256] = f2bf(h1); hr[tid + 512] = f2bf(h2);
  float p = h0 * h0 + h1 * h1 + h2 * h2;
  #pragma unroll
  for (int o = 32; o; o >>= 1) p += __shfl_xor(p, o);
  if ((tid & 63) == 0) red[8 + wv] = p;
  __syncthreads();
  if (tid == 0) row2[row] = red[8] + red[9] + red[10] + red[11];
}

// ---------------- yat GEMM: 64x128 tile, 3-buffer distance-2, XCD swizzle ---
constexpr int M_QKV = 0, M_AO = 1, M_PART = 2;

struct GemmArgs {
  const unsigned short* A; const unsigned short* Bt;
  const float* arow2; const float* wcol2; const float* bias; const float* alpha;
  int N; int ks;                                        // ks = row stride in K dim
  const float* rope;                                    // QKV
  unsigned short* qo; unsigned short* ko; unsigned short* vo;  // QKV
  const float* xf; float* xo;                           // AO: residual in/out (f32)
  float* part;                                          // PART: f32 slab base
};

template <int MODE, int NI, int NBM, int NBN, int NZ>
__global__ __launch_bounds__(256, 4) void k_gemm(GemmArgs p) {
  __shared__ __align__(16) unsigned short As[3][2048];   // 64 x 32
  __shared__ __align__(16) unsigned short Bs[3][4096];   // 128 x 32
  const int tid = threadIdx.x, wave = tid >> 6, lane = tid & 63;
  const int quad = lane >> 4, l = lane & 15;
  constexpr int TOTAL = NBM * NBN * NZ;
  const int g = xcd_swizzle(blockIdx.x, TOTAL);
  const int bm = (g % NBM) * 64;
  const int rest = g / NBM;
  const int bn = (rest % NBN) * 128;
  const int z = rest / NBN;
  const int kb = z * (NI * 32);
  const int ks = p.ks;
  const int wm = (wave & 1) * 32, wn = (wave >> 1) * 64;
  const f32x4 fzero = {0.f, 0.f, 0.f, 0.f};
  f32x4 acc[2][4];
  #pragma unroll
  for (int i = 0; i < 2; ++i)
    #pragma unroll
    for (int j = 0; j < 4; ++j) acc[i][j] = fzero;
  const int sw = (l >> 1) & 3;

  auto stage = [&](int s, int k0) {
    {
      int ci = tid;
      int r = ci >> 2;
      int c = (ci & 3) ^ ((r >> 1) & 3);
      async16(p.A + (long)(bm + r) * ks + kb + k0 + c * 8, &As[s][ci * 8]);
    }
    #pragma unroll
    for (int it = 0; it < 2; ++it) {
      int ci = tid + it * 256;
      int r = ci >> 2;
      int c = (ci & 3) ^ ((r >> 1) & 3);
      async16(p.Bt + (long)(bn + r) * ks + kb + k0 + c * 8, &Bs[s][ci * 8]);
    }
  };
  auto compute = [&](int s) {
    bf16x8 af[2], bfv[4];
    #pragma unroll
    for (int mi = 0; mi < 2; ++mi)
      af[mi] = *(const bf16x8*)&As[s][(wm + mi * 16 + l) * 32 + ((quad ^ sw) * 8)];
    #pragma unroll
    for (int ni = 0; ni < 4; ++ni)
      bfv[ni] = *(const bf16x8*)&Bs[s][(wn + ni * 16 + l) * 32 + ((quad ^ sw) * 8)];
    #pragma unroll
    for (int mi = 0; mi < 2; ++mi)
      #pragma unroll
      for (int ni = 0; ni < 4; ++ni)
        acc[mi][ni] = __builtin_amdgcn_mfma_f32_16x16x32_bf16(af[mi], bfv[ni], acc[mi][ni], 0, 0, 0);
  };
  auto iter = [&](int s, int i) {
    if (i + 1 >= NI) { asm volatile("s_waitcnt vmcnt(0)" ::: "memory"); }
    else             { asm volatile("s_waitcnt vmcnt(3)" ::: "memory"); }
    __builtin_amdgcn_s_barrier();
    asm volatile("" ::: "memory");
    if (i + 2 < NI) stage(s == 0 ? 2 : s - 1, (i + 2) * 32);
    compute(s);
  };

  stage(0, 0);
  stage(1, 32);
  int i = 0;
  while (i < NI) {          // NI % 3 == 0
    iter(0, i); ++i;
    iter(1, i); ++i;
    iter(2, i); ++i;
  }

  if constexpr (MODE == M_PART) {
    float* slab = p.part + (long)z * (2048 * 768);
    #pragma unroll
    for (int ni = 0; ni < 4; ++ni) {
      const int j = bn + wn + ni * 16 + l;
      #pragma unroll
      for (int mi = 0; mi < 2; ++mi) {
        const int i0 = bm + wm + mi * 16 + quad * 4;
        #pragma unroll
        for (int rg = 0; rg < 4; ++rg)
          slab[(long)(i0 + rg) * 768 + j] = acc[mi][ni][rg];
      }
    }
  } else {
    const float al = p.alpha[0];
    const float nn = (float)p.N;
    const float ys = powf(sqrtf(nn) / log1pf(nn), al);
    #pragma unroll
    for (int ni = 0; ni < 4; ++ni) {
      const int j = bn + wn + ni * 16 + l;
      const float w2 = p.wcol2[j];
      const float bj = p.bias[j];
      int s3 = 0, hh = 0, dd = 0;
      if constexpr (MODE == M_QKV) { s3 = j / 768; int rem = j - s3 * 768; hh = rem >> 6; dd = rem & 63; }
      #pragma unroll
      for (int mi = 0; mi < 2; ++mi) {
        const int i0 = bm + wm + mi * 16 + quad * 4;
        float vv[4];
        #pragma unroll
        for (int rg = 0; rg < 4; ++rg) {
          const float y = acc[mi][ni][rg];
          const float dist = p.arow2[i0 + rg] + w2 - 2.f * y + 1e-6f;
          vv[rg] = (y * y / dist + bj) * ys;
        }
        if constexpr (MODE == M_QKV) {
          int b = i0 >> 10, t0 = i0 & 1023;
          if (s3 == 2) {
            us4 pk = {f2bf(vv[0]), f2bf(vv[1]), f2bf(vv[2]), f2bf(vv[3])};
            *(us4*)&p.vo[((long)(b * 12 + hh) * 64 + dd) * 1024 + t0] = pk;    // V^T (B,H,D,T)
          } else {
            unsigned short* dst = (s3 == 0) ? p.qo : p.ko;                     // (B,H,T,D)
            #pragma unroll
            for (int rg = 0; rg < 4; ++rg) {
              float ro = p.rope[(t0 + rg) * 64 + dd];
              dst[((long)(b * 12 + hh) * 1024 + t0 + rg) * 64 + dd] = f2bf(vv[rg] * ro);
            }
          }
        } else {  // M_AO
          #pragma unroll
          for (int rg = 0; rg < 4; ++rg) {
            long idx = (long)(i0 + rg) * 768 + j;
            p.xo[idx] = p.xf[idx] + vv[rg];
          }
        }
      }
    }
  }
}

// ---------------- PROJ reduce (2 slabs) + yat epilogue + residual -----------
struct EpiArgs {
  const float* slab; const float* arow2; const float* wcol2;
  const float* bias; const float* alpha; const float* xo; float* outf;
};
__global__ __launch_bounds__(256) void k_proj_epi(EpiArgs p) {
  int g = blockIdx.x * 256 + threadIdx.x;   // 393216 = 2048*768/4
  int i = g / 192, jv = (g - i * 192) * 4;
  long base = (long)i * 768 + jv;
  f32x4 y = *(const f32x4*)(p.slab + base);
  y += *(const f32x4*)(p.slab + 1572864 + base);
  const float a2 = p.arow2[i];
  const float ys = powf(sqrtf(768.f) / log1pf(768.f), p.alpha[0]);
  f32x4 xo4 = *(const f32x4*)(p.xo + base);
  f32x4 out;
  #pragma unroll
  for (int c = 0; c < 4; ++c) {
    float yy = y[c];
    float dist = a2 + p.wcol2[jv + c] - 2.f * yy + 1e-6f;
    out[c] = xo4[c] + (yy * yy / dist + p.bias[jv + c]) * ys;
  }
  *(f32x4*)(p.outf + base) = out;
}

// ---------------- merged FC+GATE yat GEMM (128x128, 3-buffer dist-2) --------
struct MlpArgs {
  const unsigned short* A; const unsigned short* Bf; const unsigned short* Bg;
  const float* arow2; const float* w2f; const float* w2g;
  const float* bf; const float* bg; const float* af_; const float* ag_;
  unsigned short* mlp; float* mrow2;
};

__global__ __launch_bounds__(256, 2) void k_mlp(MlpArgs p) {
  constexpr int NI = 24, K = 768;
  __shared__ __align__(16) unsigned short As[3][4096];
  __shared__ __align__(16) unsigned short Bfs[3][4096];
  __shared__ __align__(16) unsigned short Bgs[3][4096];
  const int tid = threadIdx.x, wave = tid >> 6, lane = tid & 63;
  const int quad = lane >> 4, l = lane & 15;
  const int g = xcd_swizzle(blockIdx.x, 16 * 24);
  const int bm = (g % 16) * 128, bn = (g / 16) * 128;
  const int wm = (wave & 1) * 64, wn = (wave >> 1) * 64;
  const f32x4 fzero = {0.f, 0.f, 0.f, 0.f};
  f32x4 accf[4][4], accg[4][4];
  #pragma unroll
  for (int i = 0; i < 4; ++i)
    #pragma unroll
    for (int j = 0; j < 4; ++j) { accf[i][j] = fzero; accg[i][j] = fzero; }
  const int sw = (l >> 1) & 3;

  auto stage = [&](int s, int k0) {
    #pragma unroll
    for (int it = 0; it < 2; ++it) {
      int ci = tid + it * 256;
      int r = ci >> 2;
      int c = (ci & 3) ^ ((r >> 1) & 3);
      async16(p.A  + (long)(bm + r) * K + k0 + c * 8, &As[s][ci * 8]);
      async16(p.Bf + (long)(bn + r) * K + k0 + c * 8, &Bfs[s][ci * 8]);
      async16(p.Bg + (long)(bn + r) * K + k0 + c * 8, &Bgs[s][ci * 8]);
    }
  };
  auto compute = [&](int s) {
    bf16x8 af[4], bff[4], bfg[4];
    #pragma unroll
    for (int mi = 0; mi < 4; ++mi)
      af[mi] = *(const bf16x8*)&As[s][(wm + mi * 16 + l) * 32 + ((quad ^ sw) * 8)];
    #pragma unroll
    for (int ni = 0; ni < 4; ++ni) {
      bff[ni] = *(const bf16x8*)&Bfs[s][(wn + ni * 16 + l) * 32 + ((quad ^ sw) * 8)];
      bfg[ni] = *(const bf16x8*)&Bgs[s][(wn + ni * 16 + l) * 32 + ((quad ^ sw) * 8)];
    }
    #pragma unroll
    for (int mi = 0; mi < 4; ++mi)
      #pragma unroll
      for (int ni = 0; ni < 4; ++ni) {
        accf[mi][ni] = __builtin_amdgcn_mfma_f32_16x16x32_bf16(af[mi], bff[ni], accf[mi][ni], 0, 0, 0);
        accg[mi][ni] = __builtin_amdgcn_mfma_f32_16x16x32_bf16(af[mi], bfg[ni], accg[mi][ni], 0, 0, 0);
      }
  };
  auto iter = [&](int s, int i) {
    if (i + 1 >= NI) { asm volatile("s_waitcnt vmcnt(0)" ::: "memory"); }
    else             { asm volatile("s_waitcnt vmcnt(6)" ::: "memory"); }
    __builtin_amdgcn_s_barrier();
    asm volatile("" ::: "memory");
    if (i + 2 < NI) stage(s == 0 ? 2 : s - 1, (i + 2) * 32);
    compute(s);
  };

  stage(0, 0);
  stage(1, 32);
  int i = 0;
  while (i < NI) {          // NI % 3 == 0
    iter(0, i); ++i;
    iter(1, i); ++i;
    iter(2, i); ++i;
  }

  const float ysf = powf(sqrtf(3072.f) / log1pf(3072.f), p.af_[0]);
  const float ysg = powf(sqrtf(3072.f) / log1pf(3072.f), p.ag_[0]);
  float w2f[4], w2g[4], bjf[4], bjg[4]; int js[4];
  #pragma unroll
  for (int ni = 0; ni < 4; ++ni) {
    int j = bn + wn + ni * 16 + l;
    js[ni] = j; w2f[ni] = p.w2f[j]; w2g[ni] = p.w2g[j]; bjf[ni] = p.bf[j]; bjg[ni] = p.bg[j];
  }
  #pragma unroll
  for (int mi = 0; mi < 4; ++mi) {
    #pragma unroll
    for (int rg = 0; rg < 4; ++rg) {
      const int ii = bm + wm + mi * 16 + quad * 4 + rg;
      const float a2 = p.arow2[ii];
      float rsum = 0.f;
      #pragma unroll
      for (int ni = 0; ni < 4; ++ni) {
        float yf = accf[mi][ni][rg];
        float gate = (yf * yf / (a2 + w2f[ni] - 2.f * yf + 1e-6f) + bjf[ni]) * ysf;
        float yg = accg[mi][ni][rg];
        float u  = (yg * yg / (a2 + w2g[ni] - 2.f * yg + 1e-6f) + bjg[ni]) * ysg;
        float out = gelu_t(u) * gate;
        p.mlp[(long)ii * 3072 + js[ni]] = f2bf(out);
        rsum += out * out;
      }
      #pragma unroll
      for (int o = 8; o; o >>= 1) rsum += __shfl_xor(rsum, o);
      if (l == 0) atomicAdd(&p.mrow2[ii], rsum);
    }
  }
}

// ---------------- flash attention: 64-row Q tiles, causal, prefetched -------
__global__ __launch_bounds__(256) void k_attn(const unsigned short* __restrict__ qb,
    const unsigned short* __restrict__ kb, const unsigned short* __restrict__ vb,
    unsigned short* __restrict__ ob, float* __restrict__ orow2) {
  __shared__ __align__(16) unsigned short Qs[4096];
  __shared__ __align__(16) unsigned short Ks[3][4096];
  __shared__ __align__(16) unsigned short Vs[3][4096];
  __shared__ __align__(16) unsigned short Ps[4096];
  const int tid = threadIdx.x, wave = tid >> 6, lane = tid & 63;
  const int quad = lane >> 4, l = lane & 15;
  const int g = xcd_swizzle(blockIdx.x, 16 * 24);
  const int bh = g % 24, qt = 15 - (g / 24);   // heavy q-tiles first
  const int b = bh / 12, hh = bh % 12;
  const int q0 = qt * 64;
  const f32x4 fzero = {0.f, 0.f, 0.f, 0.f};

  auto stage_kv = [&](int s, int jt) {
    const unsigned short* kg = kb + ((long)bh * 1024 + jt * 64) * 64;
    const unsigned short* vg = vb + (long)bh * 64 * 1024 + jt * 64;
    #pragma unroll
    for (int it = 0; it < 2; ++it) {
      int ci = tid + it * 256;
      int r = ci >> 3;
      int c = (ci & 7) ^ (r & 7);
      async16(kg + (long)r * 64 + c * 8, &Ks[s][ci * 8]);
      async16(vg + (long)r * 1024 + c * 8, &Vs[s][ci * 8]);
    }
  };

  const unsigned short* qg = qb + ((long)bh * 1024 + q0) * 64;
  #pragma unroll
  for (int it = 0; it < 2; ++it) {
    int ci = tid + it * 256;
    int r = ci >> 3;
    int c = (ci & 7) ^ (r & 7);
    async16(qg + (long)r * 64 + c * 8, &Qs[ci * 8]);
  }
  stage_kv(0, 0);
  if (qt >= 1) {
    stage_kv(1, 1);
    asm volatile("s_waitcnt vmcnt(4)" ::: "memory");
  } else {
    asm volatile("s_waitcnt vmcnt(0)" ::: "memory");
  }
  __builtin_amdgcn_s_barrier();
  asm volatile("" ::: "memory");

  bf16x8 aq[2];
  #pragma unroll
  for (int ks = 0; ks < 2; ++ks)
    aq[ks] = *(const bf16x8*)&Qs[(wave * 16 + l) * 64 + (((ks * 4 + quad) ^ (l & 7)) * 8)];

  f32x4 O[4];
  float mi_[4], li[4];
  #pragma unroll
  for (int f = 0; f < 4; ++f) O[f] = fzero;
  #pragma unroll
  for (int r = 0; r < 4; ++r) { mi_[r] = -1e30f; li[r] = 0.f; }

  for (int jt = 0; jt <= qt; ++jt) {
    const int s = jt % 3;
    if (jt > 0) {
      if (jt + 1 <= qt) { asm volatile("s_waitcnt vmcnt(4)" ::: "memory"); }
      else              { asm volatile("s_waitcnt vmcnt(0)" ::: "memory"); }
      __builtin_amdgcn_s_barrier();
      asm volatile("" ::: "memory");
    }
    if (jt + 2 <= qt) stage_kv((jt + 2) % 3, jt + 2);

    f32x4 S[4];
    #pragma unroll
    for (int f = 0; f < 4; ++f) S[f] = fzero;
    #pragma unroll
    for (int ks = 0; ks < 2; ++ks) {
      #pragma unroll
      for (int f = 0; f < 4; ++f) {
        bf16x8 bk = *(const bf16x8*)&Ks[s][(f * 16 + l) * 64 + (((ks * 4 + quad) ^ (l & 7)) * 8)];
        S[f] = __builtin_amdgcn_mfma_f32_16x16x32_bf16(aq[ks], bk, S[f], 0, 0, 0);
      }
    }
    const bool diag = (jt == qt);
    #pragma unroll
    for (int f = 0; f < 4; ++f)
      #pragma unroll
      for (int r = 0; r < 4; ++r) {
        float v = S[f][r] * 0.125f;
        if (diag && (f * 16 + l > wave * 16 + quad * 4 + r)) v = -1e30f;
        S[f][r] = v;
      }
    #pragma unroll
    for (int r = 0; r < 4; ++r) {
      float mx = fmaxf(fmaxf(S[0][r], S[1][r]), fmaxf(S[2][r], S[3][r]));
      #pragma unroll
      for (int o = 8; o; o >>= 1) mx = fmaxf(mx, __shfl_xor(mx, o));
      float mnew = fmaxf(mi_[r], mx);
      float alr = __expf(mi_[r] - mnew);
      float sum = 0.f;
      #pragma unroll
      for (int f = 0; f < 4; ++f) {
        float e = __expf(S[f][r] - mnew);
        S[f][r] = e;
        sum += e;
      }
      #pragma unroll
      for (int o = 8; o; o >>= 1) sum += __shfl_xor(sum, o);
      li[r] = li[r] * alr + sum;
      #pragma unroll
      for (int f = 0; f < 4; ++f) O[f][r] *= alr;
      mi_[r] = mnew;
    }
    // P: C-layout -> wave-private LDS strip -> A-layout (in-wave, ds-ordered)
    #pragma unroll
    for (int f = 0; f < 4; ++f)
      #pragma unroll
      for (int r = 0; r < 4; ++r) {
        int i = quad * 4 + r;
        int j = f * 16 + l;
        int pch = (j >> 3) ^ (i & 7);
        Ps[wave * 1024 + i * 64 + pch * 8 + (j & 7)] = f2bf(S[f][r]);
      }
    #pragma unroll
    for (int ks = 0; ks < 2; ++ks) {
      bf16x8 ap = *(const bf16x8*)&Ps[wave * 1024 + l * 64 + (((ks * 4 + quad) ^ (l & 7)) * 8)];
      #pragma unroll
      for (int f = 0; f < 4; ++f) {
        bf16x8 bv = *(const bf16x8*)&Vs[s][(f * 16 + l) * 64 + (((ks * 4 + quad) ^ (l & 7)) * 8)];
        O[f] = __builtin_amdgcn_mfma_f32_16x16x32_bf16(ap, bv, O[f], 0, 0, 0);
      }
    }
  }
  #pragma unroll
  for (int f = 0; f < 4; ++f)
    #pragma unroll
    for (int r = 0; r < 4; ++r) {
      int t = q0 + wave * 16 + quad * 4 + r;
      int dd = f * 16 + l;
      float v = O[f][r] / li[r];
      ob[((long)(b * 1024 + t) * 12 + hh) * 64 + dd] = f2bf(v);  // (B,T,H,D)
    }
  #pragma unroll
  for (int r = 0; r < 4; ++r) {
    float rsum = 0.f;
    #pragma unroll
    for (int f = 0; f < 4; ++f) { float v = O[f][r] / li[r]; rsum += v * v; }
    #pragma unroll
    for (int o = 8; o; o >>= 1) rsum += __shfl_xor(rsum, o);
    if (l == 0) {
      int t = q0 + wave * 16 + quad * 4 + r;
      atomicAdd(&orow2[b * 1024 + t], rsum);
    }
  }
}

// ---------------- host ------------------------------------------------------
extern "C" void kernel_launch(void* const* d_in, const int* in_sizes, int n_in,
                              void* d_out, int out_size, void* d_ws, size_t ws_size,
                              hipStream_t stream) {
  (void)in_sizes; (void)n_in; (void)out_size;
  char* w = (char*)d_ws;
  size_t off = 0;
  auto alloc = [&](size_t bytes) -> void* {
    void* p = w + off;
    off = (off + bytes + 255) & ~(size_t)255;
    return p;
  };
  float* rope            = (float*)alloc(65536 * 4);
  unsigned short* wtqkv  = (unsigned short*)alloc((size_t)2304 * 768 * 2);
  unsigned short* wtao   = (unsigned short*)alloc((size_t)768 * 768 * 2);
  unsigned short* wtfc   = (unsigned short*)alloc((size_t)3072 * 768 * 2);
  unsigned short* wtgate = (unsigned short*)alloc((size_t)3072 * 768 * 2);
  unsigned short* wtproj = (unsigned short*)alloc((size_t)768 * 3072 * 2);
  float* zeroed          = (float*)alloc(14080 * 4);   // wcol2(9984) + orow2(2048) + mrow2(2048)
  unsigned short* h1     = (unsigned short*)alloc((size_t)2048 * 768 * 2);
  float* hrow1           = (float*)alloc(2048 * 4);
  unsigned short* qbuf   = (unsigned short*)alloc((size_t)2048 * 768 * 2);
  unsigned short* kbuf   = (unsigned short*)alloc((size_t)2048 * 768 * 2);
  unsigned short* vbuf   = (unsigned short*)alloc((size_t)2048 * 768 * 2);
  unsigned short* obuf   = (unsigned short*)alloc((size_t)2048 * 768 * 2);
  float* xo              = (float*)alloc((size_t)2048 * 768 * 4);
  unsigned short* h2     = (unsigned short*)alloc((size_t)2048 * 768 * 2);
  float* hrow2           = (float*)alloc(2048 * 4);
  unsigned short* mlp    = (unsigned short*)alloc((size_t)2048 * 3072 * 2);
  float* slabs           = (float*)alloc((size_t)2 * 2048 * 768 * 4);  // PROJ split-K partials
  if (off > ws_size) return;

  float* wcol2  = zeroed;
  float* orow2  = zeroed + 9984;
  float* mrow2  = zeroed + 9984 + 2048;
  float* c_qkv  = wcol2 + 0;
  float* c_ao   = wcol2 + 2304;
  float* c_fc   = wcol2 + 3072;
  float* c_gate = wcol2 + 6144;
  float* c_proj = wcol2 + 9216;

  const float* xin = (const float*)d_in[0];

  hipMemsetAsync(zeroed, 0, 14080 * 4, stream);

  // merged prep: rope(256) + transpose(9216) + LN1(2048) = 11520 blocks
  PrepArgs pa;
  pa.rope = rope;
  pa.W[0] = (const float*)d_in[3];  pa.Wt[0] = wtqkv;  pa.cn[0] = c_qkv;  pa.N[0] = 2304;
  pa.W[1] = (const float*)d_in[6];  pa.Wt[1] = wtao;   pa.cn[1] = c_ao;   pa.N[1] = 768;
  pa.W[2] = (const float*)d_in[10]; pa.Wt[2] = wtfc;   pa.cn[2] = c_fc;   pa.N[2] = 3072;
  pa.W[3] = (const float*)d_in[13]; pa.Wt[3] = wtgate; pa.cn[3] = c_gate; pa.N[3] = 3072;
  pa.W[4] = (const float*)d_in[16]; pa.Wt[4] = wtproj; pa.cn[4] = c_proj; pa.N[4] = 768;
  pa.off[0] = 0; pa.off[1] = 1728; pa.off[2] = 2304; pa.off[3] = 4608;
  pa.off[4] = 6912; pa.off[5] = 9216;
  pa.x = xin; pa.g1s = (const float*)d_in[2]; pa.h1 = h1; pa.hrow1 = hrow1;
  k_prep<<<11520, 256, 0, stream>>>(pa);

  GemmArgs gq = {};
  gq.A = h1; gq.Bt = wtqkv; gq.arow2 = hrow1; gq.wcol2 = c_qkv;
  gq.bias = (const float*)d_in[4]; gq.alpha = (const float*)d_in[5];
  gq.N = 2304; gq.ks = 768;
  gq.rope = rope; gq.qo = qbuf; gq.ko = kbuf; gq.vo = vbuf;
  k_gemm<M_QKV, 24, 32, 18, 1><<<576, 256, 0, stream>>>(gq);

  k_attn<<<384, 256, 0, stream>>>(qbuf, kbuf, vbuf, obuf, orow2);

  GemmArgs ga = {};
  ga.A = obuf; ga.Bt = wtao; ga.arow2 = orow2; ga.wcol2 = c_ao;
  ga.bias = (const float*)d_in[7]; ga.alpha = (const float*)d_in[8];
  ga.N = 768; ga.ks = 768;
  ga.xf = xin; ga.xo = xo;
  k_gemm<M_AO, 24, 32, 6, 1><<<192, 256, 0, stream>>>(ga);

  k_ln<<<2048, 256, 0, stream>>>(xo, (const float*)d_in[9], h2, hrow2);

  MlpArgs gm = {};
  gm.A = h2; gm.Bf = wtfc; gm.Bg = wtgate; gm.arow2 = hrow2;
  gm.w2f = c_fc; gm.w2g = c_gate;
  gm.bf = (const float*)d_in[11]; gm.bg = (const float*)d_in[14];
  gm.af_ = (const float*)d_in[12]; gm.ag_ = (const float*)d_in[15];
  gm.mlp = mlp; gm.mrow2 = mrow2;
  k_mlp<<<384, 256, 0, stream>>>(gm);

  GemmArgs gp = {};
  gp.A = mlp; gp.Bt = wtproj;
  gp.N = 768; gp.ks = 3072;
  gp.part = slabs;
  k_gemm<M_PART, 48, 32, 6, 2><<<384, 256, 0, stream>>>(gp);

  EpiArgs ge = {};
  ge.slab = slabs; ge.arow2 = mrow2; ge.wcol2 = c_proj;
  ge.bias = (const float*)d_in[17]; ge.alpha = (const float*)d_in[18];
  ge.xo = xo; ge.outf = (float*)d_out;
  k_proj_epi<<<1536, 256, 0, stream>>>(ge);
}

// Round 7
// 276.692 us; speedup vs baseline: 1.4909x; 1.0159x over previous
//
#include <hip/hip_runtime.h>
#include <cstdint>

#define DEVFN static __device__ __forceinline__

typedef __bf16 bf16x8 __attribute__((ext_vector_type(8)));
typedef float f32x4 __attribute__((ext_vector_type(4)));
typedef unsigned short us4 __attribute__((ext_vector_type(4)));

DEVFN unsigned short f2bf(float f) {
  unsigned u = __float_as_uint(f);
  u += 0x7fffu + ((u >> 16) & 1u);           // round-to-nearest-even
  return (unsigned short)(u >> 16);
}
DEVFN float bf2f(unsigned short h) { return __uint_as_float(((unsigned)h) << 16); }
DEVFN void async16(const void* g, void* l) {
  __builtin_amdgcn_global_load_lds((__attribute__((address_space(1))) const void*)g,
                                   (__attribute__((address_space(3))) void*)l, 16, 0, 0);
}
// gelu(tanh approx) == u * sigmoid(2z), z = 0.79788456*(u+0.044715u^3)  (exact identity)
DEVFN float gelu_t(float u) {
  float z = 0.7978845608028654f * (u + 0.044715f * u * u * u);
  float zc = fminf(fmaxf(z, -15.f), 15.f);
  float e = __expf(2.f * zc);
  return u * __fdividef(e, e + 1.f);
}
// XCD swizzle: lin%8 = XCD class; give each XCD a contiguous slice of g-space
DEVFN int xcd_swizzle(int lin, int total) {
  return (lin & 7) * (total >> 3) + (lin >> 3);
}

// ---------------- merged prep: rope + 5 transposes + LN1 --------------------
struct PrepArgs {
  float* rope;
  const float* W[5]; unsigned short* Wt[5]; float* cn[5];
  int N[5]; int off[6];
  const float* x; const float* g1s; unsigned short* h1; float* hrow1;
};
__global__ __launch_bounds__(256) void k_prep(PrepArgs a) {
  __shared__ float tile[32][33];
  __shared__ float part[8][32];
  __shared__ float red[12];
  const int bid = blockIdx.x, tid = threadIdx.x;
  if (bid < 256) {                       // rope table
    int g = bid * 256 + tid;
    int t = g >> 6, dd = g & 63, i = dd & 31;
    float fr = __expf(-0.2878231366242558f * (float)i);   // ln(1e4)/32
    float ang = (float)t * fr;
    a.rope[g] = (dd < 32) ? cosf(ang) : sinf(ang);
  } else if (bid < 9472) {               // weight transpose + col sq-norms
    int lin = bid - 256;
    int e = 0;
    while (lin >= a.off[e + 1]) ++e;
    int local = lin - a.off[e];
    const int N = a.N[e];
    int nbx = N >> 5;
    int tn = local % nbx, tk = local / nbx;
    const float* W = a.W[e];
    unsigned short* Wt = a.Wt[e];
    float* cn = a.cn[e];
    const int K = (e == 4) ? 3072 : 768;
    int tx = tid & 31, ty = tid >> 5;
    float acc = 0.f;
    #pragma unroll
    for (int j = 0; j < 4; ++j) {
      int r = ty + j * 8;
      float v = W[(long)(tk * 32 + r) * N + tn * 32 + tx];
      tile[r][tx] = v;
      acc += v * v;
    }
    part[ty][tx] = acc;
    __syncthreads();
    #pragma unroll
    for (int j = 0; j < 4; ++j) {
      int rr = ty + j * 8;
      Wt[(long)(tn * 32 + rr) * K + tk * 32 + tx] = f2bf(tile[tx][rr]);
    }
    if (ty == 0) {
      float s = part[0][tx];
      #pragma unroll
      for (int jj = 1; jj < 8; ++jj) s += part[jj][tx];
      atomicAdd(&cn[tn * 32 + tx], s);
    }
  } else {                               // LN1
    int row = bid - 9472;
    const float* xr = a.x + (long)row * 768;
    float v0 = xr[tid], v1 = xr[tid + 256], v2 = xr[tid + 512];
    float s = v0 + v1 + v2;
    float ss = v0 * v0 + v1 * v1 + v2 * v2;
    #pragma unroll
    for (int o = 32; o; o >>= 1) { s += __shfl_xor(s, o); ss += __shfl_xor(ss, o); }
    int wv = tid >> 6;
    if ((tid & 63) == 0) { red[wv] = s; red[wv + 4] = ss; }
    __syncthreads();
    s = red[0] + red[1] + red[2] + red[3];
    ss = red[4] + red[5] + red[6] + red[7];
    float mu = s * (1.f / 768.f);
    float var = ss * (1.f / 768.f) - mu * mu;
    float rs = rsqrtf(var + 1e-6f);
    float h0 = (v0 - mu) * rs * a.g1s[tid];
    float h1 = (v1 - mu) * rs * a.g1s[tid + 256];
    float h2 = (v2 - mu) * rs * a.g1s[tid + 512];
    unsigned short* hr = a.h1 + (long)row * 768;
    hr[tid] = f2bf(h0); hr[tid + 256] = f2bf(h1); hr[tid + 512] = f2bf(h2);
    float p = h0 * h0 + h1 * h1 + h2 * h2;
    #pragma unroll
    for (int o = 32; o; o >>= 1) p += __shfl_xor(p, o);
    if ((tid & 63) == 0) red[8 + wv] = p;
    __syncthreads();
    if (tid == 0) a.hrow1[row] = red[8] + red[9] + red[10] + red[11];
  }
}

// ---------------- layernorm (f32 in) -> bf16 h + row sum(h^2) ---------------
__global__ __launch_bounds__(256) void k_ln(const float* __restrict__ x,
    const float* __restrict__ g, unsigned short* __restrict__ h, float* __restrict__ row2) {
  int row = blockIdx.x, tid = threadIdx.x;
  const float* xr = x + (long)row * 768;
  float v0 = xr[tid], v1 = xr[tid + 256], v2 = xr[tid + 512];
  float s = v0 + v1 + v2;
  float ss = v0 * v0 + v1 * v1 + v2 * v2;
  #pragma unroll
  for (int o = 32; o; o >>= 1) { s += __shfl_xor(s, o); ss += __shfl_xor(ss, o); }
  __shared__ float red[12];
  int wv = tid >> 6;
  if ((tid & 63) == 0) { red[wv] = s; red[wv + 4] = ss; }
  __syncthreads();
  s = red[0] + red[1] + red[2] + red[3];
  ss = red[4] + red[5] + red[6] + red[7];
  float mu = s * (1.f / 768.f);
  float var = ss * (1.f / 768.f) - mu * mu;
  float rs = rsqrtf(var + 1e-6f);
  float h0 = (v0 - mu) * rs * g[tid];
  float h1 = (v1 - mu) * rs * g[tid + 256];
  float h2 = (v2 - mu) * rs * g[tid + 512];
  unsigned short* hr = h + (long)row * 768;
  hr[tid] = f2bf(h0); hr[tid + 256] = f2bf(h1); hr[tid + 512] = f2bf(h2);
  float p = h0 * h0 + h1 * h1 + h2 * h2;
  #pragma unroll
  for (int o = 32; o; o >>= 1) p += __shfl_xor(p, o);
  if ((tid & 63) == 0) red[8 + wv] = p;
  __syncthreads();
  if (tid == 0) row2[row] = red[8] + red[9] + red[10] + red[11];
}

// ---------------- yat GEMM: 64x128 tile, 3-buffer distance-2, XCD swizzle ---
constexpr int M_QKV = 0, M_AO = 1, M_PART = 2;

struct GemmArgs {
  const unsigned short* A; const unsigned short* Bt;
  const float* arow2; const float* wcol2; const float* bias; const float* alpha;
  int N; int ks;
  const float* rope;                                    // QKV
  unsigned short* qo; unsigned short* ko; unsigned short* vo;  // QKV
  const float* xf; float* xo;                           // AO: residual in/out (f32)
  unsigned short* partb;                                // PART: bf16 slab base
};

template <int MODE, int NI, int NBM, int NBN, int NZ>
__global__ __launch_bounds__(256, 4) void k_gemm(GemmArgs p) {
  __shared__ __align__(16) unsigned short As[3][2048];   // 64 x 32
  __shared__ __align__(16) unsigned short Bs[3][4096];   // 128 x 32
  const int tid = threadIdx.x, wave = tid >> 6, lane = tid & 63;
  const int quad = lane >> 4, l = lane & 15;
  constexpr int TOTAL = NBM * NBN * NZ;
  const int g = xcd_swizzle(blockIdx.x, TOTAL);
  const int bm = (g % NBM) * 64;
  const int rest = g / NBM;
  const int bn = (rest % NBN) * 128;
  const int z = rest / NBN;
  const int kb = z * (NI * 32);
  const int ks = p.ks;
  const int wm = (wave & 1) * 32, wn = (wave >> 1) * 64;
  const f32x4 fzero = {0.f, 0.f, 0.f, 0.f};
  f32x4 acc[2][4];
  #pragma unroll
  for (int i = 0; i < 2; ++i)
    #pragma unroll
    for (int j = 0; j < 4; ++j) acc[i][j] = fzero;
  const int sw = (l >> 1) & 3;

  auto stage = [&](int s, int k0) {
    {
      int ci = tid;
      int r = ci >> 2;
      int c = (ci & 3) ^ ((r >> 1) & 3);
      async16(p.A + (long)(bm + r) * ks + kb + k0 + c * 8, &As[s][ci * 8]);
    }
    #pragma unroll
    for (int it = 0; it < 2; ++it) {
      int ci = tid + it * 256;
      int r = ci >> 2;
      int c = (ci & 3) ^ ((r >> 1) & 3);
      async16(p.Bt + (long)(bn + r) * ks + kb + k0 + c * 8, &Bs[s][ci * 8]);
    }
  };
  auto compute = [&](int s) {
    bf16x8 af[2], bfv[4];
    #pragma unroll
    for (int mi = 0; mi < 2; ++mi)
      af[mi] = *(const bf16x8*)&As[s][(wm + mi * 16 + l) * 32 + ((quad ^ sw) * 8)];
    #pragma unroll
    for (int ni = 0; ni < 4; ++ni)
      bfv[ni] = *(const bf16x8*)&Bs[s][(wn + ni * 16 + l) * 32 + ((quad ^ sw) * 8)];
    #pragma unroll
    for (int mi = 0; mi < 2; ++mi)
      #pragma unroll
      for (int ni = 0; ni < 4; ++ni)
        acc[mi][ni] = __builtin_amdgcn_mfma_f32_16x16x32_bf16(af[mi], bfv[ni], acc[mi][ni], 0, 0, 0);
  };
  auto iter = [&](int s, int i) {
    if (i + 1 >= NI) { asm volatile("s_waitcnt vmcnt(0)" ::: "memory"); }
    else             { asm volatile("s_waitcnt vmcnt(3)" ::: "memory"); }
    __builtin_amdgcn_s_barrier();
    asm volatile("" ::: "memory");
    if (i + 2 < NI) stage(s == 0 ? 2 : s - 1, (i + 2) * 32);
    compute(s);
  };

  stage(0, 0);
  stage(1, 32);
  int i = 0;
  while (i < NI) {          // NI % 3 == 0
    iter(0, i); ++i;
    iter(1, i); ++i;
    iter(2, i); ++i;
  }

  if constexpr (MODE == M_PART) {
    unsigned short* slab = p.partb + (long)z * (2048 * 768);
    #pragma unroll
    for (int ni = 0; ni < 4; ++ni) {
      const int j = bn + wn + ni * 16 + l;
      #pragma unroll
      for (int mi = 0; mi < 2; ++mi) {
        const int i0 = bm + wm + mi * 16 + quad * 4;
        #pragma unroll
        for (int rg = 0; rg < 4; ++rg)
          slab[(long)(i0 + rg) * 768 + j] = f2bf(acc[mi][ni][rg]);
      }
    }
  } else {
    const float al = p.alpha[0];
    const float nn = (float)p.N;
    const float ys = powf(sqrtf(nn) / log1pf(nn), al);
    #pragma unroll
    for (int ni = 0; ni < 4; ++ni) {
      const int j = bn + wn + ni * 16 + l;
      const float w2 = p.wcol2[j];
      const float bj = p.bias[j];
      int s3 = 0, hh = 0, dd = 0;
      if constexpr (MODE == M_QKV) { s3 = j / 768; int rem = j - s3 * 768; hh = rem >> 6; dd = rem & 63; }
      #pragma unroll
      for (int mi = 0; mi < 2; ++mi) {
        const int i0 = bm + wm + mi * 16 + quad * 4;
        float vv[4];
        #pragma unroll
        for (int rg = 0; rg < 4; ++rg) {
          const float y = acc[mi][ni][rg];
          const float dist = p.arow2[i0 + rg] + w2 - 2.f * y + 1e-6f;
          vv[rg] = (__fdividef(y * y, dist) + bj) * ys;
        }
        if constexpr (MODE == M_QKV) {
          int b = i0 >> 10, t0 = i0 & 1023;
          if (s3 == 2) {
            us4 pk = {f2bf(vv[0]), f2bf(vv[1]), f2bf(vv[2]), f2bf(vv[3])};
            *(us4*)&p.vo[((long)(b * 12 + hh) * 64 + dd) * 1024 + t0] = pk;    // V^T (B,H,D,T)
          } else {
            unsigned short* dst = (s3 == 0) ? p.qo : p.ko;                     // (B,H,T,D)
            #pragma unroll
            for (int rg = 0; rg < 4; ++rg) {
              float ro = p.rope[(t0 + rg) * 64 + dd];
              dst[((long)(b * 12 + hh) * 1024 + t0 + rg) * 64 + dd] = f2bf(vv[rg] * ro);
            }
          }
        } else {  // M_AO
          #pragma unroll
          for (int rg = 0; rg < 4; ++rg) {
            long idx = (long)(i0 + rg) * 768 + j;
            p.xo[idx] = p.xf[idx] + vv[rg];
          }
        }
      }
    }
  }
}

// ---------------- PROJ reduce (4 bf16 slabs) + yat epilogue + residual ------
struct EpiArgs {
  const unsigned short* slab; const float* arow2; const float* wcol2;
  const float* bias; const float* alpha; const float* xo; float* outf;
};
__global__ __launch_bounds__(256) void k_proj_epi(EpiArgs p) {
  int g = blockIdx.x * 256 + threadIdx.x;   // 393216 = 2048*768/4
  int i = g / 192, jv = (g - i * 192) * 4;
  long base = (long)i * 768 + jv;
  f32x4 y = {0.f, 0.f, 0.f, 0.f};
  #pragma unroll
  for (int z = 0; z < 4; ++z) {
    us4 s4 = *(const us4*)(p.slab + (long)z * 1572864 + base);
    #pragma unroll
    for (int c = 0; c < 4; ++c) y[c] += bf2f(s4[c]);
  }
  const float a2 = p.arow2[i];
  const float ys = powf(sqrtf(768.f) / log1pf(768.f), p.alpha[0]);
  f32x4 xo4 = *(const f32x4*)(p.xo + base);
  f32x4 out;
  #pragma unroll
  for (int c = 0; c < 4; ++c) {
    float yy = y[c];
    float dist = a2 + p.wcol2[jv + c] - 2.f * yy + 1e-6f;
    out[c] = xo4[c] + (__fdividef(yy * yy, dist) + p.bias[jv + c]) * ys;
  }
  *(f32x4*)(p.outf + base) = out;
}

// ---- merged FC+GATE yat GEMM: 64x128, A direct->VGPR, B 3-buffer dist-2 ----
struct MlpArgs {
  const unsigned short* A; const unsigned short* Bf; const unsigned short* Bg;
  const float* arow2; const float* w2f; const float* w2g;
  const float* bf; const float* bg; const float* af_; const float* ag_;
  unsigned short* mlp; float* mrow2;
};

__global__ __launch_bounds__(256, 3) void k_mlp(MlpArgs p) {
  constexpr int NI = 24, K = 768;
  __shared__ __align__(16) unsigned short Bfs[3][4096];
  __shared__ __align__(16) unsigned short Bgs[3][4096];
  const int tid = threadIdx.x, wave = tid >> 6, lane = tid & 63;
  const int quad = lane >> 4, l = lane & 15;
  const int g = xcd_swizzle(blockIdx.x, 32 * 24);
  const int bm = (g % 32) * 64, bn = (g / 32) * 128;
  const int wm = (wave & 1) * 32, wn = (wave >> 1) * 64;
  const f32x4 fzero = {0.f, 0.f, 0.f, 0.f};
  f32x4 accf[2][4], accg[2][4];
  #pragma unroll
  for (int i = 0; i < 2; ++i)
    #pragma unroll
    for (int j = 0; j < 4; ++j) { accf[i][j] = fzero; accg[i][j] = fzero; }
  const int sw = (l >> 1) & 3;

  auto stageB = [&](int s, int k0) {
    #pragma unroll
    for (int it = 0; it < 2; ++it) {
      int ci = tid + it * 256;
      int r = ci >> 2;
      int c = (ci & 3) ^ ((r >> 1) & 3);
      async16(p.Bf + (long)(bn + r) * K + k0 + c * 8, &Bfs[s][ci * 8]);
      async16(p.Bg + (long)(bn + r) * K + k0 + c * 8, &Bgs[s][ci * 8]);
    }
  };

  stageB(0, 0);
  stageB(1, 32);
  const unsigned short* Arow0 = p.A + (long)(bm + wm + l) * K + quad * 8;
  const unsigned short* Arow1 = Arow0 + 16 * K;
  for (int i = 0; i < NI; ++i) {
    const int s = i % 3;
    const int k0 = i * 32;
    // A fragments direct from global (issued BEFORE the vmcnt so the
    // compiler's A-use wait (vmcnt(4)) never drains the B prefetch).
    bf16x8 af0 = *(const bf16x8*)(Arow0 + k0);
    bf16x8 af1 = *(const bf16x8*)(Arow1 + k0);
    if (i + 1 >= NI) { asm volatile("s_waitcnt vmcnt(2)" ::: "memory"); }
    else             { asm volatile("s_waitcnt vmcnt(6)" ::: "memory"); }
    __builtin_amdgcn_s_barrier();
    asm volatile("" ::: "memory");
    if (i + 2 < NI) stageB((i + 2) % 3, (i + 2) * 32);
    bf16x8 bff[4], bfg[4];
    #pragma unroll
    for (int ni = 0; ni < 4; ++ni) {
      bff[ni] = *(const bf16x8*)&Bfs[s][(wn + ni * 16 + l) * 32 + ((quad ^ sw) * 8)];
      bfg[ni] = *(const bf16x8*)&Bgs[s][(wn + ni * 16 + l) * 32 + ((quad ^ sw) * 8)];
    }
    #pragma unroll
    for (int ni = 0; ni < 4; ++ni) {
      accf[0][ni] = __builtin_amdgcn_mfma_f32_16x16x32_bf16(af0, bff[ni], accf[0][ni], 0, 0, 0);
      accg[0][ni] = __builtin_amdgcn_mfma_f32_16x16x32_bf16(af0, bfg[ni], accg[0][ni], 0, 0, 0);
      accf[1][ni] = __builtin_amdgcn_mfma_f32_16x16x32_bf16(af1, bff[ni], accf[1][ni], 0, 0, 0);
      accg[1][ni] = __builtin_amdgcn_mfma_f32_16x16x32_bf16(af1, bfg[ni], accg[1][ni], 0, 0, 0);
    }
  }

  const float ysf = powf(sqrtf(3072.f) / log1pf(3072.f), p.af_[0]);
  const float ysg = powf(sqrtf(3072.f) / log1pf(3072.f), p.ag_[0]);
  float w2f[4], w2g[4], bjf[4], bjg[4]; int js[4];
  #pragma unroll
  for (int ni = 0; ni < 4; ++ni) {
    int j = bn + wn + ni * 16 + l;
    js[ni] = j; w2f[ni] = p.w2f[j]; w2g[ni] = p.w2g[j]; bjf[ni] = p.bf[j]; bjg[ni] = p.bg[j];
  }
  #pragma unroll
  for (int mi = 0; mi < 2; ++mi) {
    #pragma unroll
    for (int rg = 0; rg < 4; ++rg) {
      const int ii = bm + wm + mi * 16 + quad * 4 + rg;
      const float a2 = p.arow2[ii];
      float rsum = 0.f;
      #pragma unroll
      for (int ni = 0; ni < 4; ++ni) {
        float yf = accf[mi][ni][rg];
        float gate = (__fdividef(yf * yf, a2 + w2f[ni] - 2.f * yf + 1e-6f) + bjf[ni]) * ysf;
        float yg = accg[mi][ni][rg];
        float u  = (__fdividef(yg * yg, a2 + w2g[ni] - 2.f * yg + 1e-6f) + bjg[ni]) * ysg;
        float out = gelu_t(u) * gate;
        p.mlp[(long)ii * 3072 + js[ni]] = f2bf(out);
        rsum += out * out;
      }
      #pragma unroll
      for (int o = 8; o; o >>= 1) rsum += __shfl_xor(rsum, o);
      if (l == 0) atomicAdd(&p.mrow2[ii], rsum);
    }
  }
}

// ---------------- flash attention: 64-row Q tiles, causal, prefetched -------
__global__ __launch_bounds__(256) void k_attn(const unsigned short* __restrict__ qb,
    const unsigned short* __restrict__ kb, const unsigned short* __restrict__ vb,
    unsigned short* __restrict__ ob, float* __restrict__ orow2) {
  __shared__ __align__(16) unsigned short Qs[4096];
  __shared__ __align__(16) unsigned short Ks[3][4096];
  __shared__ __align__(16) unsigned short Vs[3][4096];
  __shared__ __align__(16) unsigned short Ps[4096];
  const int tid = threadIdx.x, wave = tid >> 6, lane = tid & 63;
  const int quad = lane >> 4, l = lane & 15;
  const int g = xcd_swizzle(blockIdx.x, 16 * 24);
  const int bh = g % 24, qt = 15 - (g / 24);   // heavy q-tiles first
  const int b = bh / 12, hh = bh % 12;
  const int q0 = qt * 64;
  const f32x4 fzero = {0.f, 0.f, 0.f, 0.f};

  auto stage_kv = [&](int s, int jt) {
    const unsigned short* kg = kb + ((long)bh * 1024 + jt * 64) * 64;
    const unsigned short* vg = vb + (long)bh * 64 * 1024 + jt * 64;
    #pragma unroll
    for (int it = 0; it < 2; ++it) {
      int ci = tid + it * 256;
      int r = ci >> 3;
      int c = (ci & 7) ^ (r & 7);
      async16(kg + (long)r * 64 + c * 8, &Ks[s][ci * 8]);
      async16(vg + (long)r * 1024 + c * 8, &Vs[s][ci * 8]);
    }
  };

  const unsigned short* qg = qb + ((long)bh * 1024 + q0) * 64;
  #pragma unroll
  for (int it = 0; it < 2; ++it) {
    int ci = tid + it * 256;
    int r = ci >> 3;
    int c = (ci & 7) ^ (r & 7);
    async16(qg + (long)r * 64 + c * 8, &Qs[ci * 8]);
  }
  stage_kv(0, 0);
  if (qt >= 1) {
    stage_kv(1, 1);
    asm volatile("s_waitcnt vmcnt(4)" ::: "memory");
  } else {
    asm volatile("s_waitcnt vmcnt(0)" ::: "memory");
  }
  __builtin_amdgcn_s_barrier();
  asm volatile("" ::: "memory");

  bf16x8 aq[2];
  #pragma unroll
  for (int ks = 0; ks < 2; ++ks)
    aq[ks] = *(const bf16x8*)&Qs[(wave * 16 + l) * 64 + (((ks * 4 + quad) ^ (l & 7)) * 8)];

  f32x4 O[4];
  float mi_[4], li[4];
  #pragma unroll
  for (int f = 0; f < 4; ++f) O[f] = fzero;
  #pragma unroll
  for (int r = 0; r < 4; ++r) { mi_[r] = -1e30f; li[r] = 0.f; }

  for (int jt = 0; jt <= qt; ++jt) {
    const int s = jt % 3;
    if (jt > 0) {
      if (jt + 1 <= qt) { asm volatile("s_waitcnt vmcnt(4)" ::: "memory"); }
      else              { asm volatile("s_waitcnt vmcnt(0)" ::: "memory"); }
      __builtin_amdgcn_s_barrier();
      asm volatile("" ::: "memory");
    }
    if (jt + 2 <= qt) stage_kv((jt + 2) % 3, jt + 2);

    f32x4 S[4];
    #pragma unroll
    for (int f = 0; f < 4; ++f) S[f] = fzero;
    #pragma unroll
    for (int ks = 0; ks < 2; ++ks) {
      #pragma unroll
      for (int f = 0; f < 4; ++f) {
        bf16x8 bk = *(const bf16x8*)&Ks[s][(f * 16 + l) * 64 + (((ks * 4 + quad) ^ (l & 7)) * 8)];
        S[f] = __builtin_amdgcn_mfma_f32_16x16x32_bf16(aq[ks], bk, S[f], 0, 0, 0);
      }
    }
    const bool diag = (jt == qt);
    #pragma unroll
    for (int f = 0; f < 4; ++f)
      #pragma unroll
      for (int r = 0; r < 4; ++r) {
        float v = S[f][r] * 0.125f;
        if (diag && (f * 16 + l > wave * 16 + quad * 4 + r)) v = -1e30f;
        S[f][r] = v;
      }
    #pragma unroll
    for (int r = 0; r < 4; ++r) {
      float mx = fmaxf(fmaxf(S[0][r], S[1][r]), fmaxf(S[2][r], S[3][r]));
      #pragma unroll
      for (int o = 8; o; o >>= 1) mx = fmaxf(mx, __shfl_xor(mx, o));
      float mnew = fmaxf(mi_[r], mx);
      float alr = __expf(mi_[r] - mnew);
      float sum = 0.f;
      #pragma unroll
      for (int f = 0; f < 4; ++f) {
        float e = __expf(S[f][r] - mnew);
        S[f][r] = e;
        sum += e;
      }
      #pragma unroll
      for (int o = 8; o; o >>= 1) sum += __shfl_xor(sum, o);
      li[r] = li[r] * alr + sum;
      #pragma unroll
      for (int f = 0; f < 4; ++f) O[f][r] *= alr;
      mi_[r] = mnew;
    }
    #pragma unroll
    for (int f = 0; f < 4; ++f)
      #pragma unroll
      for (int r = 0; r < 4; ++r) {
        int i = quad * 4 + r;
        int j = f * 16 + l;
        int pch = (j >> 3) ^ (i & 7);
        Ps[wave * 1024 + i * 64 + pch * 8 + (j & 7)] = f2bf(S[f][r]);
      }
    #pragma unroll
    for (int ks = 0; ks < 2; ++ks) {
      bf16x8 ap = *(const bf16x8*)&Ps[wave * 1024 + l * 64 + (((ks * 4 + quad) ^ (l & 7)) * 8)];
      #pragma unroll
      for (int f = 0; f < 4; ++f) {
        bf16x8 bv = *(const bf16x8*)&Vs[s][(f * 16 + l) * 64 + (((ks * 4 + quad) ^ (l & 7)) * 8)];
        O[f] = __builtin_amdgcn_mfma_f32_16x16x32_bf16(ap, bv, O[f], 0, 0, 0);
      }
    }
  }
  float inv[4];
  #pragma unroll
  for (int r = 0; r < 4; ++r) inv[r] = __fdividef(1.f, li[r]);
  #pragma unroll
  for (int f = 0; f < 4; ++f)
    #pragma unroll
    for (int r = 0; r < 4; ++r) {
      int t = q0 + wave * 16 + quad * 4 + r;
      int dd = f * 16 + l;
      ob[((long)(b * 1024 + t) * 12 + hh) * 64 + dd] = f2bf(O[f][r] * inv[r]);  // (B,T,H,D)
    }
  #pragma unroll
  for (int r = 0; r < 4; ++r) {
    float rsum = 0.f;
    #pragma unroll
    for (int f = 0; f < 4; ++f) { float v = O[f][r] * inv[r]; rsum += v * v; }
    #pragma unroll
    for (int o = 8; o; o >>= 1) rsum += __shfl_xor(rsum, o);
    if (l == 0) {
      int t = q0 + wave * 16 + quad * 4 + r;
      atomicAdd(&orow2[b * 1024 + t], rsum);
    }
  }
}

// ---------------- host ------------------------------------------------------
extern "C" void kernel_launch(void* const* d_in, const int* in_sizes, int n_in,
                              void* d_out, int out_size, void* d_ws, size_t ws_size,
                              hipStream_t stream) {
  (void)in_sizes; (void)n_in; (void)out_size;
  char* w = (char*)d_ws;
  size_t off = 0;
  auto alloc = [&](size_t bytes) -> void* {
    void* p = w + off;
    off = (off + bytes + 255) & ~(size_t)255;
    return p;
  };
  float* rope            = (float*)alloc(65536 * 4);
  unsigned short* wtqkv  = (unsigned short*)alloc((size_t)2304 * 768 * 2);
  unsigned short* wtao   = (unsigned short*)alloc((size_t)768 * 768 * 2);
  unsigned short* wtfc   = (unsigned short*)alloc((size_t)3072 * 768 * 2);
  unsigned short* wtgate = (unsigned short*)alloc((size_t)3072 * 768 * 2);
  unsigned short* wtproj = (unsigned short*)alloc((size_t)768 * 3072 * 2);
  float* zeroed          = (float*)alloc(14080 * 4);   // wcol2(9984) + orow2(2048) + mrow2(2048)
  unsigned short* h1     = (unsigned short*)alloc((size_t)2048 * 768 * 2);
  float* hrow1           = (float*)alloc(2048 * 4);
  unsigned short* qbuf   = (unsigned short*)alloc((size_t)2048 * 768 * 2);
  unsigned short* kbuf   = (unsigned short*)alloc((size_t)2048 * 768 * 2);
  unsigned short* vbuf   = (unsigned short*)alloc((size_t)2048 * 768 * 2);
  unsigned short* obuf   = (unsigned short*)alloc((size_t)2048 * 768 * 2);
  float* xo              = (float*)alloc((size_t)2048 * 768 * 4);
  unsigned short* h2     = (unsigned short*)alloc((size_t)2048 * 768 * 2);
  float* hrow2           = (float*)alloc(2048 * 4);
  unsigned short* mlp    = (unsigned short*)alloc((size_t)2048 * 3072 * 2);
  unsigned short* slabs  = (unsigned short*)alloc((size_t)4 * 2048 * 768 * 2);  // bf16 split-K partials
  if (off > ws_size) return;

  float* wcol2  = zeroed;
  float* orow2  = zeroed + 9984;
  float* mrow2  = zeroed + 9984 + 2048;
  float* c_qkv  = wcol2 + 0;
  float* c_ao   = wcol2 + 2304;
  float* c_fc   = wcol2 + 3072;
  float* c_gate = wcol2 + 6144;
  float* c_proj = wcol2 + 9216;

  const float* xin = (const float*)d_in[0];

  hipMemsetAsync(zeroed, 0, 14080 * 4, stream);

  PrepArgs pa;
  pa.rope = rope;
  pa.W[0] = (const float*)d_in[3];  pa.Wt[0] = wtqkv;  pa.cn[0] = c_qkv;  pa.N[0] = 2304;
  pa.W[1] = (const float*)d_in[6];  pa.Wt[1] = wtao;   pa.cn[1] = c_ao;   pa.N[1] = 768;
  pa.W[2] = (const float*)d_in[10]; pa.Wt[2] = wtfc;   pa.cn[2] = c_fc;   pa.N[2] = 3072;
  pa.W[3] = (const float*)d_in[13]; pa.Wt[3] = wtgate; pa.cn[3] = c_gate; pa.N[3] = 3072;
  pa.W[4] = (const float*)d_in[16]; pa.Wt[4] = wtproj; pa.cn[4] = c_proj; pa.N[4] = 768;
  pa.off[0] = 0; pa.off[1] = 1728; pa.off[2] = 2304; pa.off[3] = 4608;
  pa.off[4] = 6912; pa.off[5] = 9216;
  pa.x = xin; pa.g1s = (const float*)d_in[2]; pa.h1 = h1; pa.hrow1 = hrow1;
  k_prep<<<11520, 256, 0, stream>>>(pa);

  GemmArgs gq = {};
  gq.A = h1; gq.Bt = wtqkv; gq.arow2 = hrow1; gq.wcol2 = c_qkv;
  gq.bias = (const float*)d_in[4]; gq.alpha = (const float*)d_in[5];
  gq.N = 2304; gq.ks = 768;
  gq.rope = rope; gq.qo = qbuf; gq.ko = kbuf; gq.vo = vbuf;
  k_gemm<M_QKV, 24, 32, 18, 1><<<576, 256, 0, stream>>>(gq);

  k_attn<<<384, 256, 0, stream>>>(qbuf, kbuf, vbuf, obuf, orow2);

  GemmArgs ga = {};
  ga.A = obuf; ga.Bt = wtao; ga.arow2 = orow2; ga.wcol2 = c_ao;
  ga.bias = (const float*)d_in[7]; ga.alpha = (const float*)d_in[8];
  ga.N = 768; ga.ks = 768;
  ga.xf = xin; ga.xo = xo;
  k_gemm<M_AO, 24, 32, 6, 1><<<192, 256, 0, stream>>>(ga);

  k_ln<<<2048, 256, 0, stream>>>(xo, (const float*)d_in[9], h2, hrow2);

  MlpArgs gm = {};
  gm.A = h2; gm.Bf = wtfc; gm.Bg = wtgate; gm.arow2 = hrow2;
  gm.w2f = c_fc; gm.w2g = c_gate;
  gm.bf = (const float*)d_in[11]; gm.bg = (const float*)d_in[14];
  gm.af_ = (const float*)d_in[12]; gm.ag_ = (const float*)d_in[15];
  gm.mlp = mlp; gm.mrow2 = mrow2;
  k_mlp<<<768, 256, 0, stream>>>(gm);

  GemmArgs gp = {};
  gp.A = mlp; gp.Bt = wtproj;
  gp.N = 768; gp.ks = 3072;
  gp.partb = slabs;
  k_gemm<M_PART, 24, 32, 6, 4><<<768, 256, 0, stream>>>(gp);

  EpiArgs ge = {};
  ge.slab = slabs; ge.arow2 = mrow2; ge.wcol2 = c_proj;
  ge.bias = (const float*)d_in[17]; ge.alpha = (const float*)d_in[18];
  ge.xo = xo; ge.outf = (float*)d_out;
  k_proj_epi<<<1536, 256, 0, stream>>>(ge);
}